// Round 5
// baseline (222.543 us; speedup 1.0000x reference)
//
#include <hip/hip_runtime.h>
#include <hip/hip_bf16.h>
#include <stdint.h>

// Problem constants: B=8, S=1024, D=1024, H=16, DH=64
typedef __bf16 bf16_t;
typedef bf16_t bf16x8 __attribute__((ext_vector_type(8)));
typedef float f32x4 __attribute__((ext_vector_type(4)));
typedef unsigned short ushortx8 __attribute__((ext_vector_type(8)));

__device__ __forceinline__ uint16_t f2bf(float f) {
  uint32_t u = __float_as_uint(f);
  uint32_t r = u + 0x7FFFu + ((u >> 16) & 1u);  // RNE
  return (uint16_t)(r >> 16);
}

// Length arrays may arrive as int32 or int64; for int64 (values in [1,1024])
// the odd int32 words are zero high-halves. p[2b] is the low word -> correct
// either way once detected. (r3==r4 outputs proved int32, keep for robustness.)
__device__ __forceinline__ int read_len(const int* __restrict__ p, int b) {
  bool is64 = (p[1] == 0) | (p[3] == 0) | (p[5] == 0) | (p[7] == 0);
  return is64 ? p[2 * b] : p[b];
}

// ---------------- NT GEMM: C[M,N] = A[M,K] * Bw[N,K]^T + bias ----------------
// Both A and Bw are f32 [rows][1024]; converted to bf16 during staging.
// MODE 0: write natural layout outQ[m*1024+n] as FLOAT32 (Q into d_out), scaled.
// MODE 1: n<1024 -> K layout [B,H,S,DH] bf16; n>=1024 -> V^T [B,H,DH,S] bf16.
template <int MODE>
__global__ __launch_bounds__(256) void gemm_nt(
    const float* __restrict__ A,      // [M][1024] f32
    const float* __restrict__ Bw,     // [N][1024] f32
    const float* __restrict__ bias,   // [N] f32
    float* __restrict__ outQ,         // MODE 0 dest (natural, f32)
    uint16_t* __restrict__ outK,      // MODE 1 K dest (bf16)
    uint16_t* __restrict__ outV,      // MODE 1 Vt dest (bf16)
    float scale) {
  __shared__ __attribute__((aligned(16))) uint16_t As[128 * 64];
  __shared__ __attribute__((aligned(16))) uint16_t Bs[128 * 64];
  const int t = threadIdx.x;
  const int lane = t & 63;
  const int w = t >> 6;
  const int wm = w >> 1, wn = w & 1;
  const int bn = blockIdx.x * 128;
  const int bm = blockIdx.y * 128;
  const int l15 = lane & 15, lg = lane >> 4;

  f32x4 acc[4][4];
#pragma unroll
  for (int i = 0; i < 4; ++i)
#pragma unroll
    for (int j = 0; j < 4; ++j) acc[i][j] = (f32x4){0.f, 0.f, 0.f, 0.f};

  for (int kt = 0; kt < 1024; kt += 64) {
    // Stage A and B: f32 global -> bf16 regs -> linear ds_write_b128.
#pragma unroll
    for (int i = 0; i < 4; ++i) {
      int L = t + 256 * i;           // granule (row, k8)
      int row = L >> 3, k8 = L & 7;
      {
        const float* src = A + (size_t)(bm + row) * 1024 + kt + k8 * 8;
        float4 v0 = *reinterpret_cast<const float4*>(src);
        float4 v1 = *reinterpret_cast<const float4*>(src + 4);
        ushortx8 o;
        o[0] = f2bf(v0.x); o[1] = f2bf(v0.y); o[2] = f2bf(v0.z); o[3] = f2bf(v0.w);
        o[4] = f2bf(v1.x); o[5] = f2bf(v1.y); o[6] = f2bf(v1.z); o[7] = f2bf(v1.w);
        *reinterpret_cast<ushortx8*>(As + L * 8) = o;
      }
      {
        const float* src = Bw + (size_t)(bn + row) * 1024 + kt + k8 * 8;
        float4 v0 = *reinterpret_cast<const float4*>(src);
        float4 v1 = *reinterpret_cast<const float4*>(src + 4);
        ushortx8 o;
        o[0] = f2bf(v0.x); o[1] = f2bf(v0.y); o[2] = f2bf(v0.z); o[3] = f2bf(v0.w);
        o[4] = f2bf(v1.x); o[5] = f2bf(v1.y); o[6] = f2bf(v1.z); o[7] = f2bf(v1.w);
        *reinterpret_cast<ushortx8*>(Bs + L * 8) = o;
      }
    }
    __syncthreads();

#pragma unroll
    for (int ks = 0; ks < 2; ++ks) {
      const int kb = ks * 32 + lg * 8;  // element offset within a 64-elem row
      bf16x8 af[4], bf[4];
#pragma unroll
      for (int mf = 0; mf < 4; ++mf) {
        int row = wm * 64 + mf * 16 + l15;
        af[mf] = *reinterpret_cast<const bf16x8*>(As + row * 64 + kb);
      }
#pragma unroll
      for (int nf = 0; nf < 4; ++nf) {
        int row = wn * 64 + nf * 16 + l15;
        bf[nf] = *reinterpret_cast<const bf16x8*>(Bs + row * 64 + kb);
      }
#pragma unroll
      for (int mf = 0; mf < 4; ++mf)
#pragma unroll
        for (int nf = 0; nf < 4; ++nf)
          acc[mf][nf] = __builtin_amdgcn_mfma_f32_16x16x32_bf16(
              af[mf], bf[nf], acc[mf][nf], 0, 0, 0);
    }
    __syncthreads();
  }

  // Epilogue: add bias, scale, scatter.
#pragma unroll
  for (int mf = 0; mf < 4; ++mf) {
#pragma unroll
    for (int nf = 0; nf < 4; ++nf) {
      int n = bn + wn * 64 + nf * 16 + l15;
      float bv = bias[n];
#pragma unroll
      for (int r = 0; r < 4; ++r) {
        int m = bm + wm * 64 + mf * 16 + lg * 4 + r;
        float v = (acc[mf][nf][r] + bv) * scale;
        if (MODE == 0) {
          outQ[(size_t)m * 1024 + n] = v;  // natural [B,S,D], f32
        } else {
          uint16_t o = f2bf(v);
          int b = m >> 10, s = m & 1023;
          if (n < 1024) {
            int h = n >> 6, d = n & 63;
            outK[((((b * 16 + h) << 10) | s) << 6) | d] = o;
          } else {
            int n2 = n - 1024;
            int h = n2 >> 6, d = n2 & 63;
            outV[((((b * 16 + h) << 6) | d) << 10) | s] = o;
          }
        }
      }
    }
  }
}

// ---------------- Flash attention ----------------
// Grid: (S/64, B*H). Block: 256 threads = 4 waves, 16 q-rows each.
// Q (f32, pre-scaled) is read from qout = d_out, natural [B,S,D] layout:
// block (q0,bh) reads exactly the 64x64 region it later overwrites with f32 out.
__global__ __launch_bounds__(256) void attn_kernel(
    float* qout,                      // d_out: Q in, attention out (aliased)
    const uint16_t* __restrict__ Kb,  // [B,H,S,DH] bf16
    const uint16_t* __restrict__ Vt,  // [B,H,DH,S] bf16
    const int* __restrict__ l_en_p, const int* __restrict__ l_fr_p) {
  __shared__ __attribute__((aligned(16))) uint16_t Ks[64 * 64];
  __shared__ __attribute__((aligned(16))) uint16_t Vs[64 * 64];
  __shared__ __attribute__((aligned(16))) bf16_t Ps[4][16][72];
  const int t = threadIdx.x;
  const int lane = t & 63, w = t >> 6;
  const int l15 = lane & 15, lg = lane >> 4;
  const int bh = blockIdx.y;
  const int b = bh >> 4, h = bh & 15;
  const int q0 = blockIdx.x * 64;
  const int len_en = read_len(l_en_p, b);
  const int len_fr = read_len(l_fr_p, b);

  if (q0 >= len_fr) {
    // fully masked query rows -> 0 (must write: out is poisoned).
    for (int i = t; i < 64 * 64; i += 256) {
      int rr = i >> 6, cc = i & 63;
      qout[(size_t)(b * 1024 + q0 + rr) * 1024 + h * 64 + cc] = 0.f;
    }
    return;
  }

  // Hoist this wave's Q fragments (16 rows x 64) from f32 into bf16 registers.
  const float* qbase =
      qout + (size_t)(b * 1024 + q0 + w * 16 + l15) * 1024 + h * 64;
  float4 q00 = *reinterpret_cast<const float4*>(qbase + lg * 8);
  float4 q01 = *reinterpret_cast<const float4*>(qbase + lg * 8 + 4);
  float4 q10 = *reinterpret_cast<const float4*>(qbase + 32 + lg * 8);
  float4 q11 = *reinterpret_cast<const float4*>(qbase + 32 + lg * 8 + 4);
  bf16x8 aq0, aq1;
  aq0[0] = (bf16_t)q00.x; aq0[1] = (bf16_t)q00.y; aq0[2] = (bf16_t)q00.z;
  aq0[3] = (bf16_t)q00.w; aq0[4] = (bf16_t)q01.x; aq0[5] = (bf16_t)q01.y;
  aq0[6] = (bf16_t)q01.z; aq0[7] = (bf16_t)q01.w;
  aq1[0] = (bf16_t)q10.x; aq1[1] = (bf16_t)q10.y; aq1[2] = (bf16_t)q10.z;
  aq1[3] = (bf16_t)q10.w; aq1[4] = (bf16_t)q11.x; aq1[5] = (bf16_t)q11.y;
  aq1[6] = (bf16_t)q11.z; aq1[7] = (bf16_t)q11.w;

  float mrow[4], lrow[4];
  f32x4 oacc[4];
#pragma unroll
  for (int r = 0; r < 4; ++r) { mrow[r] = -1e30f; lrow[r] = 0.f; }
#pragma unroll
  for (int df = 0; df < 4; ++df) oacc[df] = (f32x4){0.f, 0.f, 0.f, 0.f};

  const int ntiles = (len_en + 63) >> 6;
  for (int tt = 0; tt < ntiles; ++tt) {
    const int j0 = tt * 64;
    // Stage K tile [64 j][64 d] and V tile [64 d][64 j], linear LDS.
#pragma unroll
    for (int i = 0; i < 2; ++i) {
      int g = t + 256 * i;
      int row = g >> 3, k8 = g & 7;
      ushortx8 kv = *reinterpret_cast<const ushortx8*>(
          Kb + ((size_t)bh * 1024 + j0 + row) * 64 + k8 * 8);
      *reinterpret_cast<ushortx8*>(Ks + g * 8) = kv;
      ushortx8 vv = *reinterpret_cast<const ushortx8*>(
          Vt + ((size_t)bh * 64 + row) * 1024 + j0 + k8 * 8);
      *reinterpret_cast<ushortx8*>(Vs + g * 8) = vv;
    }
    __syncthreads();

    // Scores: S = Q * K^T  (16x64 per wave), f32.
    f32x4 sc[4];
#pragma unroll
    for (int nf = 0; nf < 4; ++nf) sc[nf] = (f32x4){0.f, 0.f, 0.f, 0.f};
#pragma unroll
    for (int ks = 0; ks < 2; ++ks) {
      const bf16x8 aq = ks ? aq1 : aq0;
      const int kb = ks * 32 + lg * 8;
#pragma unroll
      for (int nf = 0; nf < 4; ++nf) {
        int row = nf * 16 + l15;
        bf16x8 bk = *reinterpret_cast<const bf16x8*>(Ks + row * 64 + kb);
        sc[nf] = __builtin_amdgcn_mfma_f32_16x16x32_bf16(aq, bk, sc[nf], 0, 0, 0);
      }
    }
    // Key mask.
#pragma unroll
    for (int nf = 0; nf < 4; ++nf) {
      int col = j0 + nf * 16 + l15;
      if (col >= len_en) sc[nf] = (f32x4){-1e30f, -1e30f, -1e30f, -1e30f};
    }
    // Row max (reduce over 4 nf then over the row's 16 lanes).
    float tm[4];
#pragma unroll
    for (int r = 0; r < 4; ++r)
      tm[r] = fmaxf(fmaxf(sc[0][r], sc[1][r]), fmaxf(sc[2][r], sc[3][r]));
#pragma unroll
    for (int off = 1; off < 16; off <<= 1)
#pragma unroll
      for (int r = 0; r < 4; ++r) tm[r] = fmaxf(tm[r], __shfl_xor(tm[r], off));

    float fac[4];
#pragma unroll
    for (int r = 0; r < 4; ++r) {
      float mn = fmaxf(mrow[r], tm[r]);
      fac[r] = __expf(mrow[r] - mn);
      mrow[r] = mn;
    }
    // P = exp(S - m), accumulate row sums, write P to LDS for transpose.
    float ps[4] = {0.f, 0.f, 0.f, 0.f};
#pragma unroll
    for (int nf = 0; nf < 4; ++nf)
#pragma unroll
      for (int r = 0; r < 4; ++r) {
        float p = __expf(sc[nf][r] - mrow[r]);
        ps[r] += p;
        Ps[w][lg * 4 + r][nf * 16 + l15] = (bf16_t)p;
      }
#pragma unroll
    for (int off = 1; off < 16; off <<= 1)
#pragma unroll
      for (int r = 0; r < 4; ++r) ps[r] += __shfl_xor(ps[r], off);
#pragma unroll
    for (int r = 0; r < 4; ++r) lrow[r] = lrow[r] * fac[r] + ps[r];
#pragma unroll
    for (int df = 0; df < 4; ++df)
#pragma unroll
      for (int r = 0; r < 4; ++r) oacc[df][r] *= fac[r];

    // Fence: P stores must be visible to the transposed reads below.
    __syncthreads();

    // PV: O += P * V.
#pragma unroll
    for (int ks = 0; ks < 2; ++ks) {
      const bf16x8 pa = *reinterpret_cast<const bf16x8*>(
          &Ps[w][l15][0] + ks * 32 + lg * 8);
#pragma unroll
      for (int df = 0; df < 4; ++df) {
        int row = df * 16 + l15;
        bf16x8 bv = *reinterpret_cast<const bf16x8*>(
            Vs + row * 64 + ks * 32 + lg * 8);
        oacc[df] = __builtin_amdgcn_mfma_f32_16x16x32_bf16(pa, bv, oacc[df], 0, 0, 0);
      }
    }
    __syncthreads();
  }

  // Epilogue: normalize, zero masked query rows, store f32 over the Q region.
#pragma unroll
  for (int df = 0; df < 4; ++df)
#pragma unroll
    for (int r = 0; r < 4; ++r) {
      int q = q0 + w * 16 + lg * 4 + r;
      float inv = (q < len_fr && lrow[r] > 0.f) ? 1.0f / lrow[r] : 0.f;
      qout[(size_t)(b * 1024 + q) * 1024 + h * 64 + df * 16 + l15] =
          oacc[df][r] * inv;
    }
}

// ---------------- launch ----------------
extern "C" void kernel_launch(void* const* d_in, const int* in_sizes, int n_in,
                              void* d_out, int out_size, void* d_ws,
                              size_t ws_size, hipStream_t stream) {
  const float* en = (const float*)d_in[0];
  const float* fr = (const float*)d_in[1];
  const int* l_en = (const int*)d_in[2];
  const int* l_fr = (const int*)d_in[3];
  const float* wq = (const float*)d_in[4];
  const float* bq = (const float*)d_in[5];
  const float* wkv = (const float*)d_in[6];
  const float* bkv = (const float*)d_in[7];
  float* out = (float*)d_out;  // reference output dtype is FLOAT32

  // Workspace: K (16.78 MB) + Vt (16.78 MB) = 33.55 MB, bf16.
  char* ws = (char*)d_ws;
  uint16_t* Kbuf = (uint16_t*)(ws);
  uint16_t* Vtbuf = (uint16_t*)(ws + 16777216);

  // Q = fr @ W_Q^T + b_q, pre-scaled by 1/sqrt(D)=1/32, f32 natural in d_out.
  gemm_nt<0><<<dim3(8, 64), 256, 0, stream>>>(fr, wq, bq, out, nullptr, nullptr,
                                              0.03125f);
  // KV = en @ W_KV^T + b_kv. K -> Kbuf [B,H,S,DH], V -> Vtbuf [B,H,DH,S].
  gemm_nt<1><<<dim3(16, 64), 256, 0, stream>>>(en, wkv, bkv, nullptr, Kbuf,
                                               Vtbuf, 1.0f);

  attn_kernel<<<dim3(16, 128), 256, 0, stream>>>(out, Kbuf, Vtbuf, l_en, l_fr);
}

// Round 6
// 201.927 us; speedup vs baseline: 1.1021x; 1.1021x over previous
//
#include <hip/hip_runtime.h>
#include <hip/hip_bf16.h>
#include <stdint.h>

// Problem constants: B=8, S=1024, D=1024, H=16, DH=64
typedef __bf16 bf16_t;
typedef bf16_t bf16x8 __attribute__((ext_vector_type(8)));
typedef float f32x4 __attribute__((ext_vector_type(4)));
typedef unsigned short ushortx8 __attribute__((ext_vector_type(8)));

__device__ __forceinline__ uint16_t f2bf(float f) {
  uint32_t u = __float_as_uint(f);
  uint32_t r = u + 0x7FFFu + ((u >> 16) & 1u);  // RNE
  return (uint16_t)(r >> 16);
}

__device__ __forceinline__ int read_len(const int* __restrict__ p, int b) {
  bool is64 = (p[1] == 0) | (p[3] == 0) | (p[5] == 0) | (p[7] == 0);
  return is64 ? p[2 * b] : p[b];
}

#define GLDS16(gp, lp)                                                   \
  __builtin_amdgcn_global_load_lds(                                      \
      (const __attribute__((address_space(1))) uint32_t*)(gp),           \
      (__attribute__((address_space(3))) uint32_t*)(lp), 16, 0, 0)

// ---------------- f32 -> bf16 convert (n multiple of 1024) ----------------
__global__ void cvt_kernel(const float* __restrict__ in,
                           uint16_t* __restrict__ out, int n) {
  int i = (blockIdx.x * blockDim.x + threadIdx.x) * 4;
  if (i < n) {
    const float4 v = *reinterpret_cast<const float4*>(in + i);
    ushort4 o;
    o.x = f2bf(v.x); o.y = f2bf(v.y); o.z = f2bf(v.z); o.w = f2bf(v.w);
    *reinterpret_cast<ushort4*>(out + i) = o;
  }
}

// ---------------- NT GEMM: C[M,N] = A[M,K] * Bw[N,K]^T + bias ----------------
// A f32 (converted during staging, swizzled ds_write); Bw bf16 (GLDS staged,
// pre-swizzled source). LDS reads XOR-swizzled: byte ^= (row&7)<<4.
// MODE 0: write natural layout outQ[m*1024+n] as f32 (Q into d_out), scaled.
// MODE 1: n<1024 -> K layout [B,H,S,DH] bf16; n>=1024 -> V^T [B,H,DH,S] bf16.
template <int MODE>
__global__ __launch_bounds__(256) void gemm_nt(
    const float* __restrict__ A,      // [M][1024] f32
    const uint16_t* __restrict__ Bw,  // [N][1024] bf16
    const float* __restrict__ bias,   // [N] f32
    float* __restrict__ outQ,         // MODE 0 dest (natural, f32)
    uint16_t* __restrict__ outK,      // MODE 1 K dest (bf16)
    uint16_t* __restrict__ outV,      // MODE 1 Vt dest (bf16)
    float scale) {
  __shared__ __attribute__((aligned(16))) uint16_t As[128 * 64];
  __shared__ __attribute__((aligned(16))) uint16_t Bs[128 * 64];
  const int t = threadIdx.x;
  const int lane = t & 63;
  const int w = t >> 6;
  const int wm = w >> 1, wn = w & 1;
  const int bn = blockIdx.x * 128;
  const int bm = blockIdx.y * 128;
  const int l15 = lane & 15, lg = lane >> 4;

  f32x4 acc[4][4];
#pragma unroll
  for (int i = 0; i < 4; ++i)
#pragma unroll
    for (int j = 0; j < 4; ++j) acc[i][j] = (f32x4){0.f, 0.f, 0.f, 0.f};

  for (int kt = 0; kt < 1024; kt += 64) {
    // Stage B: bf16 weights via global_load_lds (linear LDS dest, swizzled src)
#pragma unroll
    for (int i = 0; i < 4; ++i) {
      int g = t + 256 * i;            // LDS slot granule (16B units)
      int L = g ^ ((g >> 3) & 7);     // logical granule it must hold
      int row = L >> 3, k8 = L & 7;
      GLDS16(Bw + (size_t)(bn + row) * 1024 + kt + k8 * 8, Bs + g * 8);
    }
    // Stage A: f32 global -> bf16 regs -> swizzled ds_write_b128
#pragma unroll
    for (int i = 0; i < 4; ++i) {
      int L = t + 256 * i;           // logical granule (row, k8)
      int row = L >> 3, k8 = L & 7;
      const float* src = A + (size_t)(bm + row) * 1024 + kt + k8 * 8;
      float4 v0 = *reinterpret_cast<const float4*>(src);
      float4 v1 = *reinterpret_cast<const float4*>(src + 4);
      ushortx8 o;
      o[0] = f2bf(v0.x); o[1] = f2bf(v0.y); o[2] = f2bf(v0.z); o[3] = f2bf(v0.w);
      o[4] = f2bf(v1.x); o[5] = f2bf(v1.y); o[6] = f2bf(v1.z); o[7] = f2bf(v1.w);
      int byte = (row * 128 + k8 * 16) ^ ((row & 7) << 4);
      *reinterpret_cast<ushortx8*>(reinterpret_cast<char*>(As) + byte) = o;
    }
    __syncthreads();

#pragma unroll
    for (int ks = 0; ks < 2; ++ks) {
      const int kb = ks * 64 + lg * 16;  // byte offset within a 128B row
      bf16x8 af[4], bf[4];
#pragma unroll
      for (int mf = 0; mf < 4; ++mf) {
        int row = wm * 64 + mf * 16 + l15;
        int byte = (row * 128 + kb) ^ ((row & 7) << 4);
        af[mf] = *reinterpret_cast<const bf16x8*>(
            reinterpret_cast<const char*>(As) + byte);
      }
#pragma unroll
      for (int nf = 0; nf < 4; ++nf) {
        int row = wn * 64 + nf * 16 + l15;
        int byte = (row * 128 + kb) ^ ((row & 7) << 4);
        bf[nf] = *reinterpret_cast<const bf16x8*>(
            reinterpret_cast<const char*>(Bs) + byte);
      }
#pragma unroll
      for (int mf = 0; mf < 4; ++mf)
#pragma unroll
        for (int nf = 0; nf < 4; ++nf)
          acc[mf][nf] = __builtin_amdgcn_mfma_f32_16x16x32_bf16(
              af[mf], bf[nf], acc[mf][nf], 0, 0, 0);
    }
    __syncthreads();
  }

  // Epilogue: add bias, scale, scatter.
#pragma unroll
  for (int mf = 0; mf < 4; ++mf) {
#pragma unroll
    for (int nf = 0; nf < 4; ++nf) {
      int n = bn + wn * 64 + nf * 16 + l15;
      float bv = bias[n];
#pragma unroll
      for (int r = 0; r < 4; ++r) {
        int m = bm + wm * 64 + mf * 16 + lg * 4 + r;
        float v = (acc[mf][nf][r] + bv) * scale;
        if (MODE == 0) {
          outQ[(size_t)m * 1024 + n] = v;  // natural [B,S,D], f32
        } else {
          uint16_t o = f2bf(v);
          int b = m >> 10, s = m & 1023;
          if (n < 1024) {
            int h = n >> 6, d = n & 63;
            outK[((((b * 16 + h) << 10) | s) << 6) | d] = o;
          } else {
            int n2 = n - 1024;
            int h = n2 >> 6, d = n2 & 63;
            outV[((((b * 16 + h) << 6) | d) << 10) | s] = o;
          }
        }
      }
    }
  }
}

// ---------------- Flash attention ----------------
// Grid: (S/64, B*H). Block: 256 threads = 4 waves, 16 q-rows each.
// Q (f32, pre-scaled) read from qout = d_out, natural [B,S,D]; block (q0,bh)
// reads exactly the 64x64 region it later overwrites with the f32 output.
__global__ __launch_bounds__(256) void attn_kernel(
    float* qout,                      // d_out: Q in, attention out (aliased)
    const uint16_t* __restrict__ Kb,  // [B,H,S,DH] bf16
    const uint16_t* __restrict__ Vt,  // [B,H,DH,S] bf16
    const int* __restrict__ l_en_p, const int* __restrict__ l_fr_p) {
  __shared__ __attribute__((aligned(16))) uint16_t Ks[64 * 64];
  __shared__ __attribute__((aligned(16))) uint16_t Vs[64 * 64];
  __shared__ __attribute__((aligned(16))) bf16_t Ps[4][16][72];
  const int t = threadIdx.x;
  const int lane = t & 63, w = t >> 6;
  const int l15 = lane & 15, lg = lane >> 4;
  const int bh = blockIdx.y;
  const int b = bh >> 4, h = bh & 15;
  const int q0 = blockIdx.x * 64;
  const int len_en = read_len(l_en_p, b);
  const int len_fr = read_len(l_fr_p, b);

  if (q0 >= len_fr) {
    for (int i = t; i < 64 * 64; i += 256) {
      int rr = i >> 6, cc = i & 63;
      qout[(size_t)(b * 1024 + q0 + rr) * 1024 + h * 64 + cc] = 0.f;
    }
    return;
  }

  // Hoist this wave's Q fragments (16 rows x 64) from f32 into bf16 registers.
  const float* qbase =
      qout + (size_t)(b * 1024 + q0 + w * 16 + l15) * 1024 + h * 64;
  float4 q00 = *reinterpret_cast<const float4*>(qbase + lg * 8);
  float4 q01 = *reinterpret_cast<const float4*>(qbase + lg * 8 + 4);
  float4 q10 = *reinterpret_cast<const float4*>(qbase + 32 + lg * 8);
  float4 q11 = *reinterpret_cast<const float4*>(qbase + 32 + lg * 8 + 4);
  bf16x8 aq0, aq1;
  aq0[0] = (bf16_t)q00.x; aq0[1] = (bf16_t)q00.y; aq0[2] = (bf16_t)q00.z;
  aq0[3] = (bf16_t)q00.w; aq0[4] = (bf16_t)q01.x; aq0[5] = (bf16_t)q01.y;
  aq0[6] = (bf16_t)q01.z; aq0[7] = (bf16_t)q01.w;
  aq1[0] = (bf16_t)q10.x; aq1[1] = (bf16_t)q10.y; aq1[2] = (bf16_t)q10.z;
  aq1[3] = (bf16_t)q10.w; aq1[4] = (bf16_t)q11.x; aq1[5] = (bf16_t)q11.y;
  aq1[6] = (bf16_t)q11.z; aq1[7] = (bf16_t)q11.w;

  float mrow[4], lrow[4];
  f32x4 oacc[4];
#pragma unroll
  for (int r = 0; r < 4; ++r) { mrow[r] = -1e30f; lrow[r] = 0.f; }
#pragma unroll
  for (int df = 0; df < 4; ++df) oacc[df] = (f32x4){0.f, 0.f, 0.f, 0.f};

  const int ntiles = (len_en + 63) >> 6;
  for (int tt = 0; tt < ntiles; ++tt) {
    const int j0 = tt * 64;
    // Stage K tile [64 j][64 d] and V tile [64 d][64 j] via GLDS,
    // linear LDS dest + swizzled global source.
#pragma unroll
    for (int i = 0; i < 2; ++i) {
      int g = t + 256 * i;
      int L = g ^ ((g >> 3) & 7);
      int row = L >> 3, k8 = L & 7;
      GLDS16(Kb + ((size_t)bh * 1024 + j0 + row) * 64 + k8 * 8, Ks + g * 8);
      GLDS16(Vt + ((size_t)bh * 64 + row) * 1024 + j0 + k8 * 8, Vs + g * 8);
    }
    __syncthreads();

    // Scores: S = Q * K^T  (16x64 per wave), f32.
    f32x4 sc[4];
#pragma unroll
    for (int nf = 0; nf < 4; ++nf) sc[nf] = (f32x4){0.f, 0.f, 0.f, 0.f};
#pragma unroll
    for (int ks = 0; ks < 2; ++ks) {
      const bf16x8 aq = ks ? aq1 : aq0;
      const int kb = ks * 64 + lg * 16;
#pragma unroll
      for (int nf = 0; nf < 4; ++nf) {
        int row = nf * 16 + l15;
        int byte = (row * 128 + kb) ^ ((row & 7) << 4);
        bf16x8 bk = *reinterpret_cast<const bf16x8*>(
            reinterpret_cast<const char*>(Ks) + byte);
        sc[nf] = __builtin_amdgcn_mfma_f32_16x16x32_bf16(aq, bk, sc[nf], 0, 0, 0);
      }
    }
    // Key mask.
#pragma unroll
    for (int nf = 0; nf < 4; ++nf) {
      int col = j0 + nf * 16 + l15;
      if (col >= len_en) sc[nf] = (f32x4){-1e30f, -1e30f, -1e30f, -1e30f};
    }
    // Row max.
    float tm[4];
#pragma unroll
    for (int r = 0; r < 4; ++r)
      tm[r] = fmaxf(fmaxf(sc[0][r], sc[1][r]), fmaxf(sc[2][r], sc[3][r]));
#pragma unroll
    for (int off = 1; off < 16; off <<= 1)
#pragma unroll
      for (int r = 0; r < 4; ++r) tm[r] = fmaxf(tm[r], __shfl_xor(tm[r], off));

    float fac[4];
#pragma unroll
    for (int r = 0; r < 4; ++r) {
      float mn = fmaxf(mrow[r], tm[r]);
      fac[r] = __expf(mrow[r] - mn);
      mrow[r] = mn;
    }
    // P = exp(S - m), row sums, write P to LDS (wave-private) for transpose.
    float ps[4] = {0.f, 0.f, 0.f, 0.f};
#pragma unroll
    for (int nf = 0; nf < 4; ++nf)
#pragma unroll
      for (int r = 0; r < 4; ++r) {
        float p = __expf(sc[nf][r] - mrow[r]);
        ps[r] += p;
        Ps[w][lg * 4 + r][nf * 16 + l15] = (bf16_t)p;
      }
#pragma unroll
    for (int off = 1; off < 16; off <<= 1)
#pragma unroll
      for (int r = 0; r < 4; ++r) ps[r] += __shfl_xor(ps[r], off);
#pragma unroll
    for (int r = 0; r < 4; ++r) lrow[r] = lrow[r] * fac[r] + ps[r];
#pragma unroll
    for (int df = 0; df < 4; ++df)
#pragma unroll
      for (int r = 0; r < 4; ++r) oacc[df][r] *= fac[r];

    // PV: O += P * V. (P is wave-private; compiler inserts lgkmcnt for RAW.)
#pragma unroll
    for (int ks = 0; ks < 2; ++ks) {
      const bf16x8 pa = *reinterpret_cast<const bf16x8*>(
          &Ps[w][l15][0] + ks * 32 + lg * 8);
#pragma unroll
      for (int df = 0; df < 4; ++df) {
        int row = df * 16 + l15;
        int byte = (row * 128 + ks * 64 + lg * 16) ^ ((row & 7) << 4);
        bf16x8 bv = *reinterpret_cast<const bf16x8*>(
            reinterpret_cast<const char*>(Vs) + byte);
        oacc[df] = __builtin_amdgcn_mfma_f32_16x16x32_bf16(pa, bv, oacc[df], 0, 0, 0);
      }
    }
    __syncthreads();
  }

  // Epilogue: normalize, store f32 over the Q region.
#pragma unroll
  for (int df = 0; df < 4; ++df)
#pragma unroll
    for (int r = 0; r < 4; ++r) {
      int q = q0 + w * 16 + lg * 4 + r;
      float inv = (q < len_fr && lrow[r] > 0.f) ? 1.0f / lrow[r] : 0.f;
      qout[(size_t)(b * 1024 + q) * 1024 + h * 64 + df * 16 + l15] =
          oacc[df][r] * inv;
    }
}

// ---------------- launch ----------------
extern "C" void kernel_launch(void* const* d_in, const int* in_sizes, int n_in,
                              void* d_out, int out_size, void* d_ws,
                              size_t ws_size, hipStream_t stream) {
  const float* en = (const float*)d_in[0];
  const float* fr = (const float*)d_in[1];
  const int* l_en = (const int*)d_in[2];
  const int* l_fr = (const int*)d_in[3];
  const float* wq = (const float*)d_in[4];
  const float* bq = (const float*)d_in[5];
  const float* wkv = (const float*)d_in[6];
  const float* bkv = (const float*)d_in[7];
  float* out = (float*)d_out;  // reference output dtype is FLOAT32

  // Workspace: wq_bf 2MB | wkv_bf 4MB | K 16.78MB | Vt 16.78MB  (~41.5 MB)
  char* ws = (char*)d_ws;
  uint16_t* wq_bf = (uint16_t*)(ws);
  uint16_t* wkv_bf = (uint16_t*)(ws + 2097152);
  uint16_t* Kbuf = (uint16_t*)(ws + 6291456);
  uint16_t* Vtbuf = (uint16_t*)(ws + 23068672);

  cvt_kernel<<<1024, 256, 0, stream>>>(wq, wq_bf, 1048576);
  cvt_kernel<<<2048, 256, 0, stream>>>(wkv, wkv_bf, 2097152);

  // Q = fr @ W_Q^T + b_q, pre-scaled by 1/sqrt(D)=1/32, f32 natural in d_out.
  gemm_nt<0><<<dim3(8, 64), 256, 0, stream>>>(fr, wq_bf, bq, out, nullptr,
                                              nullptr, 0.03125f);
  // KV = en @ W_KV^T + b_kv. K -> Kbuf [B,H,S,DH], V -> Vtbuf [B,H,DH,S].
  gemm_nt<1><<<dim3(16, 64), 256, 0, stream>>>(en, wkv_bf, bkv, nullptr, Kbuf,
                                               Vtbuf, 1.0f);

  attn_kernel<<<dim3(16, 128), 256, 0, stream>>>(out, Kbuf, Vtbuf, l_en, l_fr);
}

// Round 7
// 193.358 us; speedup vs baseline: 1.1509x; 1.0443x over previous
//
#include <hip/hip_runtime.h>
#include <hip/hip_bf16.h>
#include <stdint.h>

// Problem constants: B=8, S=1024, D=1024, H=16, DH=64
typedef __bf16 bf16_t;
typedef bf16_t bf16x8 __attribute__((ext_vector_type(8)));
typedef float f32x4 __attribute__((ext_vector_type(4)));
typedef unsigned short ushortx8 __attribute__((ext_vector_type(8)));

__device__ __forceinline__ uint16_t f2bf(float f) {
  uint32_t u = __float_as_uint(f);
  uint32_t r = u + 0x7FFFu + ((u >> 16) & 1u);  // RNE
  return (uint16_t)(r >> 16);
}

__device__ __forceinline__ int read_len(const int* __restrict__ p, int b) {
  bool is64 = (p[1] == 0) | (p[3] == 0) | (p[5] == 0) | (p[7] == 0);
  return is64 ? p[2 * b] : p[b];
}

#define GLDS16(gp, lp)                                                   \
  __builtin_amdgcn_global_load_lds(                                      \
      (const __attribute__((address_space(1))) uint32_t*)(gp),           \
      (__attribute__((address_space(3))) uint32_t*)(lp), 16, 0, 0)

// ---------------- f32 -> bf16 convert ----------------
__global__ void cvt_kernel(const float* __restrict__ in,
                           uint16_t* __restrict__ out, int n) {
  int i = (blockIdx.x * blockDim.x + threadIdx.x) * 4;
  if (i < n) {
    const float4 v = *reinterpret_cast<const float4*>(in + i);
    ushort4 o;
    o.x = f2bf(v.x); o.y = f2bf(v.y); o.z = f2bf(v.z); o.w = f2bf(v.w);
    *reinterpret_cast<ushort4*>(out + i) = o;
  }
}

// -------- Fused NT GEMM: Q = fr@wq^T+bq (scaled), KV = en@wkv^T+bkv --------
// 1536 blocks, 1D, XCD-swizzled: blocks [0,512) = Q tiles, [512,1536) = KV.
// A f32 (reg-staged, converted, swizzled ds_write); Bw bf16 (GLDS, pre-swz src).
// LDS reads XOR-swizzled: byte ^= (row&7)<<4.
__global__ __launch_bounds__(256) void gemm_fused(
    const float* __restrict__ fr, const float* __restrict__ en,
    const uint16_t* __restrict__ wq, const uint16_t* __restrict__ wkv,
    const float* __restrict__ bq, const float* __restrict__ bkv,
    uint16_t* __restrict__ Qb,       // [B,H,S,DH] bf16, pre-scaled
    uint16_t* __restrict__ Kb,       // [B,H,S,DH] bf16
    uint16_t* __restrict__ Vb) {     // [B,H,DH,S] bf16
  __shared__ __attribute__((aligned(16))) uint16_t As[128 * 64];
  __shared__ __attribute__((aligned(16))) uint16_t Bs[128 * 64];
  const int t = threadIdx.x;
  const int lane = t & 63;
  const int w = t >> 6;
  const int wm = w >> 1, wn = w & 1;
  const int l15 = lane & 15, lg = lane >> 4;

  // XCD swizzle: round-robin dispatch -> contiguous logical chunk per XCD.
  const int orig = blockIdx.x;                 // 1536 = 8 * 192
  const int wgid = (orig & 7) * 192 + (orig >> 3);
  const bool isQ = wgid < 512;
  const int l = isQ ? wgid : wgid - 512;
  const int nbn_sh = isQ ? 3 : 4;              // 8 vs 16 column tiles
  const int bn = (l & ((1 << nbn_sh) - 1)) * 128;
  const int bm = (l >> nbn_sh) * 128;
  const float* A = isQ ? fr : en;
  const uint16_t* Bw = isQ ? wq : wkv;
  const float* bias = isQ ? bq : bkv;
  const float scale = isQ ? 0.03125f : 1.0f;

  f32x4 acc[4][4];
#pragma unroll
  for (int i = 0; i < 4; ++i)
#pragma unroll
    for (int j = 0; j < 4; ++j) acc[i][j] = (f32x4){0.f, 0.f, 0.f, 0.f};

  for (int kt = 0; kt < 1024; kt += 64) {
    // Stage B: bf16 weights via global_load_lds (linear dest, swizzled src).
#pragma unroll
    for (int i = 0; i < 4; ++i) {
      int g = t + 256 * i;            // LDS slot granule (16B units)
      int L = g ^ ((g >> 3) & 7);     // logical granule it must hold
      int row = L >> 3, k8 = L & 7;
      GLDS16(Bw + (size_t)(bn + row) * 1024 + kt + k8 * 8, Bs + g * 8);
    }
    // Stage A: f32 global -> bf16 regs -> swizzled ds_write_b128.
#pragma unroll
    for (int i = 0; i < 4; ++i) {
      int L = t + 256 * i;           // logical granule (row, k8)
      int row = L >> 3, k8 = L & 7;
      const float* src = A + (size_t)(bm + row) * 1024 + kt + k8 * 8;
      float4 v0 = *reinterpret_cast<const float4*>(src);
      float4 v1 = *reinterpret_cast<const float4*>(src + 4);
      ushortx8 o;
      o[0] = f2bf(v0.x); o[1] = f2bf(v0.y); o[2] = f2bf(v0.z); o[3] = f2bf(v0.w);
      o[4] = f2bf(v1.x); o[5] = f2bf(v1.y); o[6] = f2bf(v1.z); o[7] = f2bf(v1.w);
      int byte = (row * 128 + k8 * 16) ^ ((row & 7) << 4);
      *reinterpret_cast<ushortx8*>(reinterpret_cast<char*>(As) + byte) = o;
    }
    __syncthreads();

#pragma unroll
    for (int ks = 0; ks < 2; ++ks) {
      const int kb = ks * 64 + lg * 16;  // byte offset within a 128B row
      bf16x8 af[4], bf[4];
#pragma unroll
      for (int mf = 0; mf < 4; ++mf) {
        int row = wm * 64 + mf * 16 + l15;
        int byte = (row * 128 + kb) ^ ((row & 7) << 4);
        af[mf] = *reinterpret_cast<const bf16x8*>(
            reinterpret_cast<const char*>(As) + byte);
      }
#pragma unroll
      for (int nf = 0; nf < 4; ++nf) {
        int row = wn * 64 + nf * 16 + l15;
        int byte = (row * 128 + kb) ^ ((row & 7) << 4);
        bf[nf] = *reinterpret_cast<const bf16x8*>(
            reinterpret_cast<const char*>(Bs) + byte);
      }
#pragma unroll
      for (int mf = 0; mf < 4; ++mf)
#pragma unroll
        for (int nf = 0; nf < 4; ++nf)
          acc[mf][nf] = __builtin_amdgcn_mfma_f32_16x16x32_bf16(
              af[mf], bf[nf], acc[mf][nf], 0, 0, 0);
    }
    __syncthreads();
  }

  // Epilogue: add bias, scale, scatter bf16 to attention layouts.
#pragma unroll
  for (int mf = 0; mf < 4; ++mf) {
#pragma unroll
    for (int nf = 0; nf < 4; ++nf) {
      int n = bn + wn * 64 + nf * 16 + l15;
      float bv = bias[n];
#pragma unroll
      for (int r = 0; r < 4; ++r) {
        int m = bm + wm * 64 + mf * 16 + lg * 4 + r;
        float v = (acc[mf][nf][r] + bv) * scale;
        uint16_t o = f2bf(v);
        int b = m >> 10, s = m & 1023;
        if (isQ) {
          int h = n >> 6, d = n & 63;
          Qb[((((b * 16 + h) << 10) | s) << 6) | d] = o;
        } else if (n < 1024) {
          int h = n >> 6, d = n & 63;
          Kb[((((b * 16 + h) << 10) | s) << 6) | d] = o;
        } else {
          int n2 = n - 1024;
          int h = n2 >> 6, d = n2 & 63;
          Vb[((((b * 16 + h) << 6) | d) << 10) | s] = o;
        }
      }
    }
  }
}

// ---------------- Flash attention ----------------
// 1D grid 2048 blocks (XCD-swizzled), 256 threads = 4 waves, 16 q-rows each.
__global__ __launch_bounds__(256) void attn_kernel(
    const uint16_t* __restrict__ Qb,  // [B,H,S,DH] bf16, pre-scaled
    const uint16_t* __restrict__ Kb,  // [B,H,S,DH] bf16
    const uint16_t* __restrict__ Vt,  // [B,H,DH,S] bf16
    const int* __restrict__ l_en_p, const int* __restrict__ l_fr_p,
    float* __restrict__ out) {        // [B,S,D] f32
  __shared__ __attribute__((aligned(16))) uint16_t Ks[64 * 64];
  __shared__ __attribute__((aligned(16))) uint16_t Vs[64 * 64];
  __shared__ __attribute__((aligned(16))) bf16_t Ps[4][16][72];
  const int t = threadIdx.x;
  const int lane = t & 63, w = t >> 6;
  const int l15 = lane & 15, lg = lane >> 4;
  // XCD swizzle: each XCD owns 16 consecutive heads (K/V locality).
  const int orig = blockIdx.x;                 // 2048 = 8 * 256
  const int wgid = (orig & 7) * 256 + (orig >> 3);
  const int bh = wgid >> 4;
  const int q0 = (wgid & 15) << 6;
  const int b = bh >> 4, h = bh & 15;
  const int len_en = read_len(l_en_p, b);
  const int len_fr = read_len(l_fr_p, b);

  if (q0 >= len_fr) {
    for (int i = t; i < 64 * 64; i += 256) {
      int rr = i >> 6, cc = i & 63;
      out[(size_t)(b * 1024 + q0 + rr) * 1024 + h * 64 + cc] = 0.f;
    }
    return;
  }

  // Hoist this wave's Q fragments (16 rows x 64) into registers.
  const uint16_t* qbase =
      Qb + ((size_t)bh * 1024 + q0 + w * 16 + l15) * 64 + lg * 8;
  const bf16x8 aq0 = *reinterpret_cast<const bf16x8*>(qbase);
  const bf16x8 aq1 = *reinterpret_cast<const bf16x8*>(qbase + 32);

  float mrow[4], lrow[4];
  f32x4 oacc[4];
#pragma unroll
  for (int r = 0; r < 4; ++r) { mrow[r] = -1e30f; lrow[r] = 0.f; }
#pragma unroll
  for (int df = 0; df < 4; ++df) oacc[df] = (f32x4){0.f, 0.f, 0.f, 0.f};

  const int ntiles = (len_en + 63) >> 6;
  for (int tt = 0; tt < ntiles; ++tt) {
    const int j0 = tt * 64;
    // Stage K tile [64 j][64 d] and V tile [64 d][64 j] via GLDS,
    // linear LDS dest + swizzled global source.
#pragma unroll
    for (int i = 0; i < 2; ++i) {
      int g = t + 256 * i;
      int L = g ^ ((g >> 3) & 7);
      int row = L >> 3, k8 = L & 7;
      GLDS16(Kb + ((size_t)bh * 1024 + j0 + row) * 64 + k8 * 8, Ks + g * 8);
      GLDS16(Vt + ((size_t)bh * 64 + row) * 1024 + j0 + k8 * 8, Vs + g * 8);
    }
    __syncthreads();

    // Scores: S = Q * K^T  (16x64 per wave), f32.
    f32x4 sc[4];
#pragma unroll
    for (int nf = 0; nf < 4; ++nf) sc[nf] = (f32x4){0.f, 0.f, 0.f, 0.f};
#pragma unroll
    for (int ks = 0; ks < 2; ++ks) {
      const bf16x8 aq = ks ? aq1 : aq0;
      const int kb = ks * 64 + lg * 16;
#pragma unroll
      for (int nf = 0; nf < 4; ++nf) {
        int row = nf * 16 + l15;
        int byte = (row * 128 + kb) ^ ((row & 7) << 4);
        bf16x8 bk = *reinterpret_cast<const bf16x8*>(
            reinterpret_cast<const char*>(Ks) + byte);
        sc[nf] = __builtin_amdgcn_mfma_f32_16x16x32_bf16(aq, bk, sc[nf], 0, 0, 0);
      }
    }
    // Key mask.
#pragma unroll
    for (int nf = 0; nf < 4; ++nf) {
      int col = j0 + nf * 16 + l15;
      if (col >= len_en) sc[nf] = (f32x4){-1e30f, -1e30f, -1e30f, -1e30f};
    }
    // Row max.
    float tm[4];
#pragma unroll
    for (int r = 0; r < 4; ++r)
      tm[r] = fmaxf(fmaxf(sc[0][r], sc[1][r]), fmaxf(sc[2][r], sc[3][r]));
#pragma unroll
    for (int off = 1; off < 16; off <<= 1)
#pragma unroll
      for (int r = 0; r < 4; ++r) tm[r] = fmaxf(tm[r], __shfl_xor(tm[r], off));

    float fac[4];
#pragma unroll
    for (int r = 0; r < 4; ++r) {
      float mn = fmaxf(mrow[r], tm[r]);
      fac[r] = __expf(mrow[r] - mn);
      mrow[r] = mn;
    }
    // P = exp(S - m), row sums, write P to LDS (wave-private) for transpose.
    float ps[4] = {0.f, 0.f, 0.f, 0.f};
#pragma unroll
    for (int nf = 0; nf < 4; ++nf)
#pragma unroll
      for (int r = 0; r < 4; ++r) {
        float p = __expf(sc[nf][r] - mrow[r]);
        ps[r] += p;
        Ps[w][lg * 4 + r][nf * 16 + l15] = (bf16_t)p;
      }
#pragma unroll
    for (int off = 1; off < 16; off <<= 1)
#pragma unroll
      for (int r = 0; r < 4; ++r) ps[r] += __shfl_xor(ps[r], off);
#pragma unroll
    for (int r = 0; r < 4; ++r) lrow[r] = lrow[r] * fac[r] + ps[r];
#pragma unroll
    for (int df = 0; df < 4; ++df)
#pragma unroll
      for (int r = 0; r < 4; ++r) oacc[df][r] *= fac[r];

    // PV: O += P * V. (P is wave-private; compiler inserts lgkmcnt for RAW.)
#pragma unroll
    for (int ks = 0; ks < 2; ++ks) {
      const bf16x8 pa = *reinterpret_cast<const bf16x8*>(
          &Ps[w][l15][0] + ks * 32 + lg * 8);
#pragma unroll
      for (int df = 0; df < 4; ++df) {
        int row = df * 16 + l15;
        int byte = (row * 128 + ks * 64 + lg * 16) ^ ((row & 7) << 4);
        bf16x8 bv = *reinterpret_cast<const bf16x8*>(
            reinterpret_cast<const char*>(Vs) + byte);
        oacc[df] = __builtin_amdgcn_mfma_f32_16x16x32_bf16(pa, bv, oacc[df], 0, 0, 0);
      }
    }
    __syncthreads();
  }

  // Epilogue: normalize, store f32.
#pragma unroll
  for (int df = 0; df < 4; ++df)
#pragma unroll
    for (int r = 0; r < 4; ++r) {
      int q = q0 + w * 16 + lg * 4 + r;
      float inv = (q < len_fr && lrow[r] > 0.f) ? 1.0f / lrow[r] : 0.f;
      out[(size_t)(b * 1024 + q) * 1024 + h * 64 + df * 16 + l15] =
          oacc[df][r] * inv;
    }
}

// ---------------- launch ----------------
extern "C" void kernel_launch(void* const* d_in, const int* in_sizes, int n_in,
                              void* d_out, int out_size, void* d_ws,
                              size_t ws_size, hipStream_t stream) {
  const float* en = (const float*)d_in[0];
  const float* fr = (const float*)d_in[1];
  const int* l_en = (const int*)d_in[2];
  const int* l_fr = (const int*)d_in[3];
  const float* wq = (const float*)d_in[4];
  const float* bq = (const float*)d_in[5];
  const float* wkv = (const float*)d_in[6];
  const float* bkv = (const float*)d_in[7];
  float* out = (float*)d_out;  // output dtype is FLOAT32

  // Workspace (56.62 MB, proven safe in r1):
  // wq_bf 2MB | wkv_bf 4MB | Qbuf 16.78MB | Kbuf 16.78MB | Vtbuf 16.78MB
  char* ws = (char*)d_ws;
  uint16_t* wq_bf = (uint16_t*)(ws);
  uint16_t* wkv_bf = (uint16_t*)(ws + 2097152);
  uint16_t* Qbuf = (uint16_t*)(ws + 6291456);
  uint16_t* Kbuf = (uint16_t*)(ws + 23068672);
  uint16_t* Vtbuf = (uint16_t*)(ws + 39845888);

  cvt_kernel<<<1024, 256, 0, stream>>>(wq, wq_bf, 1048576);
  cvt_kernel<<<2048, 256, 0, stream>>>(wkv, wkv_bf, 2097152);

  gemm_fused<<<1536, 256, 0, stream>>>(fr, en, wq_bf, wkv_bf, bq, bkv, Qbuf,
                                       Kbuf, Vtbuf);

  attn_kernel<<<2048, 256, 0, stream>>>(Qbuf, Kbuf, Vtbuf, l_en, l_fr, out);
}

// Round 8
// 179.679 us; speedup vs baseline: 1.2386x; 1.0761x over previous
//
#include <hip/hip_runtime.h>
#include <hip/hip_bf16.h>
#include <stdint.h>

// Problem constants: B=8, S=1024, D=1024, H=16, DH=64
typedef __bf16 bf16_t;
typedef bf16_t bf16x8 __attribute__((ext_vector_type(8)));
typedef float f32x4 __attribute__((ext_vector_type(4)));
typedef unsigned short ushortx8 __attribute__((ext_vector_type(8)));

__device__ __forceinline__ uint16_t f2bf(float f) {
  uint32_t u = __float_as_uint(f);
  uint32_t r = u + 0x7FFFu + ((u >> 16) & 1u);  // RNE
  return (uint16_t)(r >> 16);
}

__device__ __forceinline__ int read_len(const int* __restrict__ p, int b) {
  bool is64 = (p[1] == 0) | (p[3] == 0) | (p[5] == 0) | (p[7] == 0);
  return is64 ? p[2 * b] : p[b];
}

#define GLDS16(gp, lp)                                                   \
  __builtin_amdgcn_global_load_lds(                                      \
      (const __attribute__((address_space(1))) uint32_t*)(gp),           \
      (__attribute__((address_space(3))) uint32_t*)(lp), 16, 0, 0)

// ------ merged f32 -> bf16 convert over up to 4 segments (granule = 4) ------
__global__ void cvt4_kernel(const float* __restrict__ s0, uint16_t* __restrict__ d0, int n0,
                            const float* __restrict__ s1, uint16_t* __restrict__ d1, int n1,
                            const float* __restrict__ s2, uint16_t* __restrict__ d2, int n2,
                            const float* __restrict__ s3, uint16_t* __restrict__ d3, int n3) {
  int e = (blockIdx.x * blockDim.x + threadIdx.x) * 4;
  const float* s;
  uint16_t* d;
  if (e < n0) { s = s0 + e; d = d0 + e; }
  else if ((e -= n0) < n1) { s = s1 + e; d = d1 + e; }
  else if ((e -= n1) < n2) { s = s2 + e; d = d2 + e; }
  else if ((e -= n2) < n3) { s = s3 + e; d = d3 + e; }
  else return;
  const float4 v = *reinterpret_cast<const float4*>(s);
  ushort4 o;
  o.x = f2bf(v.x); o.y = f2bf(v.y); o.z = f2bf(v.z); o.w = f2bf(v.w);
  *reinterpret_cast<ushort4*>(d) = o;
}

// -------- Fused NT GEMM: Q = fr@wq^T+bq (scaled), KV = en@wkv^T+bkv --------
// 1536 blocks, 1D, XCD-swizzled: logical [0,512) = Q tiles, [512,1536) = KV.
// ABF16: A staged via global_load_lds from pre-converted bf16 (fast path).
// else : A f32 reg-staged + converted + swizzled ds_write (r7 fallback).
// B always bf16 via global_load_lds. LDS reads XOR-swizzled byte^=(row&7)<<4.
template <bool ABF16>
__global__ __launch_bounds__(256) void gemm_fused(
    const float* __restrict__ frF, const float* __restrict__ enF,
    const uint16_t* __restrict__ frB, const uint16_t* __restrict__ enB,
    const uint16_t* __restrict__ wq, const uint16_t* __restrict__ wkv,
    const float* __restrict__ bq, const float* __restrict__ bkv,
    uint16_t* __restrict__ Qb,       // [B,H,S,DH] bf16, pre-scaled
    uint16_t* __restrict__ Kb,       // [B,H,S,DH] bf16
    uint16_t* __restrict__ Vb) {     // [B,H,DH,S] bf16
  __shared__ __attribute__((aligned(16))) uint16_t As[128 * 64];
  __shared__ __attribute__((aligned(16))) uint16_t Bs[128 * 64];
  const int t = threadIdx.x;
  const int lane = t & 63;
  const int w = t >> 6;
  const int wm = w >> 1, wn = w & 1;
  const int l15 = lane & 15, lg = lane >> 4;

  // XCD swizzle: round-robin dispatch -> contiguous logical chunk per XCD.
  const int orig = blockIdx.x;                 // 1536 = 8 * 192
  const int wgid = (orig & 7) * 192 + (orig >> 3);
  const bool isQ = wgid < 512;
  const int l = isQ ? wgid : wgid - 512;
  const int nbn_sh = isQ ? 3 : 4;              // 8 vs 16 column tiles
  const int bn = (l & ((1 << nbn_sh) - 1)) * 128;
  const int bm = (l >> nbn_sh) * 128;
  const uint16_t* Bw = isQ ? wq : wkv;
  const float* bias = isQ ? bq : bkv;
  const float scale = isQ ? 0.03125f : 1.0f;

  f32x4 acc[4][4];
#pragma unroll
  for (int i = 0; i < 4; ++i)
#pragma unroll
    for (int j = 0; j < 4; ++j) acc[i][j] = (f32x4){0.f, 0.f, 0.f, 0.f};

  for (int kt = 0; kt < 1024; kt += 64) {
    // Stage B: bf16 weights via global_load_lds (linear dest, swizzled src).
#pragma unroll
    for (int i = 0; i < 4; ++i) {
      int g = t + 256 * i;            // LDS slot granule (16B units)
      int L = g ^ ((g >> 3) & 7);     // logical granule it must hold
      int row = L >> 3, k8 = L & 7;
      GLDS16(Bw + (size_t)(bn + row) * 1024 + kt + k8 * 8, Bs + g * 8);
    }
    if (ABF16) {
      // Stage A: bf16 activations via global_load_lds, same pattern as B.
      const uint16_t* Ab = isQ ? frB : enB;
#pragma unroll
      for (int i = 0; i < 4; ++i) {
        int g = t + 256 * i;
        int L = g ^ ((g >> 3) & 7);
        int row = L >> 3, k8 = L & 7;
        GLDS16(Ab + (size_t)(bm + row) * 1024 + kt + k8 * 8, As + g * 8);
      }
    } else {
      // Stage A: f32 global -> bf16 regs -> swizzled ds_write_b128.
      const float* A = isQ ? frF : enF;
#pragma unroll
      for (int i = 0; i < 4; ++i) {
        int L = t + 256 * i;           // logical granule (row, k8)
        int row = L >> 3, k8 = L & 7;
        const float* src = A + (size_t)(bm + row) * 1024 + kt + k8 * 8;
        float4 v0 = *reinterpret_cast<const float4*>(src);
        float4 v1 = *reinterpret_cast<const float4*>(src + 4);
        ushortx8 o;
        o[0] = f2bf(v0.x); o[1] = f2bf(v0.y); o[2] = f2bf(v0.z); o[3] = f2bf(v0.w);
        o[4] = f2bf(v1.x); o[5] = f2bf(v1.y); o[6] = f2bf(v1.z); o[7] = f2bf(v1.w);
        int byte = (row * 128 + k8 * 16) ^ ((row & 7) << 4);
        *reinterpret_cast<ushortx8*>(reinterpret_cast<char*>(As) + byte) = o;
      }
    }
    __syncthreads();

#pragma unroll
    for (int ks = 0; ks < 2; ++ks) {
      const int kb = ks * 64 + lg * 16;  // byte offset within a 128B row
      bf16x8 af[4], bf[4];
#pragma unroll
      for (int mf = 0; mf < 4; ++mf) {
        int row = wm * 64 + mf * 16 + l15;
        int byte = (row * 128 + kb) ^ ((row & 7) << 4);
        af[mf] = *reinterpret_cast<const bf16x8*>(
            reinterpret_cast<const char*>(As) + byte);
      }
#pragma unroll
      for (int nf = 0; nf < 4; ++nf) {
        int row = wn * 64 + nf * 16 + l15;
        int byte = (row * 128 + kb) ^ ((row & 7) << 4);
        bf[nf] = *reinterpret_cast<const bf16x8*>(
            reinterpret_cast<const char*>(Bs) + byte);
      }
#pragma unroll
      for (int mf = 0; mf < 4; ++mf)
#pragma unroll
        for (int nf = 0; nf < 4; ++nf)
          acc[mf][nf] = __builtin_amdgcn_mfma_f32_16x16x32_bf16(
              af[mf], bf[nf], acc[mf][nf], 0, 0, 0);
    }
    __syncthreads();
  }

  // Epilogue: add bias, scale, scatter bf16 to attention layouts.
#pragma unroll
  for (int mf = 0; mf < 4; ++mf) {
#pragma unroll
    for (int nf = 0; nf < 4; ++nf) {
      int n = bn + wn * 64 + nf * 16 + l15;
      float bv = bias[n];
#pragma unroll
      for (int r = 0; r < 4; ++r) {
        int m = bm + wm * 64 + mf * 16 + lg * 4 + r;
        float v = (acc[mf][nf][r] + bv) * scale;
        uint16_t o = f2bf(v);
        int b = m >> 10, s = m & 1023;
        if (isQ) {
          int h = n >> 6, d = n & 63;
          Qb[((((b * 16 + h) << 10) | s) << 6) | d] = o;
        } else if (n < 1024) {
          int h = n >> 6, d = n & 63;
          Kb[((((b * 16 + h) << 10) | s) << 6) | d] = o;
        } else {
          int n2 = n - 1024;
          int h = n2 >> 6, d = n2 & 63;
          Vb[((((b * 16 + h) << 6) | d) << 10) | s] = o;
        }
      }
    }
  }
}

// ---------------- Flash attention ----------------
// 1D grid 2048 blocks (XCD-swizzled), 256 threads = 4 waves, 16 q-rows each.
__global__ __launch_bounds__(256) void attn_kernel(
    const uint16_t* __restrict__ Qb,  // [B,H,S,DH] bf16, pre-scaled
    const uint16_t* __restrict__ Kb,  // [B,H,S,DH] bf16
    const uint16_t* __restrict__ Vt,  // [B,H,DH,S] bf16
    const int* __restrict__ l_en_p, const int* __restrict__ l_fr_p,
    float* __restrict__ out) {        // [B,S,D] f32
  __shared__ __attribute__((aligned(16))) uint16_t Ks[64 * 64];
  __shared__ __attribute__((aligned(16))) uint16_t Vs[64 * 64];
  __shared__ __attribute__((aligned(16))) bf16_t Ps[4][16][72];
  const int t = threadIdx.x;
  const int lane = t & 63, w = t >> 6;
  const int l15 = lane & 15, lg = lane >> 4;
  // XCD swizzle: each XCD owns 16 consecutive heads (K/V locality).
  const int orig = blockIdx.x;                 // 2048 = 8 * 256
  const int wgid = (orig & 7) * 256 + (orig >> 3);
  const int bh = wgid >> 4;
  const int q0 = (wgid & 15) << 6;
  const int b = bh >> 4, h = bh & 15;
  const int len_en = read_len(l_en_p, b);
  const int len_fr = read_len(l_fr_p, b);

  if (q0 >= len_fr) {
    for (int i = t; i < 64 * 64; i += 256) {
      int rr = i >> 6, cc = i & 63;
      out[(size_t)(b * 1024 + q0 + rr) * 1024 + h * 64 + cc] = 0.f;
    }
    return;
  }

  // Hoist this wave's Q fragments (16 rows x 64) into registers.
  const uint16_t* qbase =
      Qb + ((size_t)bh * 1024 + q0 + w * 16 + l15) * 64 + lg * 8;
  const bf16x8 aq0 = *reinterpret_cast<const bf16x8*>(qbase);
  const bf16x8 aq1 = *reinterpret_cast<const bf16x8*>(qbase + 32);

  float mrow[4], lrow[4];
  f32x4 oacc[4];
#pragma unroll
  for (int r = 0; r < 4; ++r) { mrow[r] = -1e30f; lrow[r] = 0.f; }
#pragma unroll
  for (int df = 0; df < 4; ++df) oacc[df] = (f32x4){0.f, 0.f, 0.f, 0.f};

  const int ntiles = (len_en + 63) >> 6;
  for (int tt = 0; tt < ntiles; ++tt) {
    const int j0 = tt * 64;
    // Stage K tile [64 j][64 d] and V tile [64 d][64 j] via GLDS,
    // linear LDS dest + swizzled global source.
#pragma unroll
    for (int i = 0; i < 2; ++i) {
      int g = t + 256 * i;
      int L = g ^ ((g >> 3) & 7);
      int row = L >> 3, k8 = L & 7;
      GLDS16(Kb + ((size_t)bh * 1024 + j0 + row) * 64 + k8 * 8, Ks + g * 8);
      GLDS16(Vt + ((size_t)bh * 64 + row) * 1024 + j0 + k8 * 8, Vs + g * 8);
    }
    __syncthreads();

    // Scores: S = Q * K^T  (16x64 per wave), f32.
    f32x4 sc[4];
#pragma unroll
    for (int nf = 0; nf < 4; ++nf) sc[nf] = (f32x4){0.f, 0.f, 0.f, 0.f};
#pragma unroll
    for (int ks = 0; ks < 2; ++ks) {
      const bf16x8 aq = ks ? aq1 : aq0;
      const int kb = ks * 64 + lg * 16;
#pragma unroll
      for (int nf = 0; nf < 4; ++nf) {
        int row = nf * 16 + l15;
        int byte = (row * 128 + kb) ^ ((row & 7) << 4);
        bf16x8 bk = *reinterpret_cast<const bf16x8*>(
            reinterpret_cast<const char*>(Ks) + byte);
        sc[nf] = __builtin_amdgcn_mfma_f32_16x16x32_bf16(aq, bk, sc[nf], 0, 0, 0);
      }
    }
    // Key mask.
#pragma unroll
    for (int nf = 0; nf < 4; ++nf) {
      int col = j0 + nf * 16 + l15;
      if (col >= len_en) sc[nf] = (f32x4){-1e30f, -1e30f, -1e30f, -1e30f};
    }
    // Row max.
    float tm[4];
#pragma unroll
    for (int r = 0; r < 4; ++r)
      tm[r] = fmaxf(fmaxf(sc[0][r], sc[1][r]), fmaxf(sc[2][r], sc[3][r]));
#pragma unroll
    for (int off = 1; off < 16; off <<= 1)
#pragma unroll
      for (int r = 0; r < 4; ++r) tm[r] = fmaxf(tm[r], __shfl_xor(tm[r], off));

    float fac[4];
#pragma unroll
    for (int r = 0; r < 4; ++r) {
      float mn = fmaxf(mrow[r], tm[r]);
      fac[r] = __expf(mrow[r] - mn);
      mrow[r] = mn;
    }
    // P = exp(S - m), row sums, write P to LDS (wave-private) for transpose.
    float ps[4] = {0.f, 0.f, 0.f, 0.f};
#pragma unroll
    for (int nf = 0; nf < 4; ++nf)
#pragma unroll
      for (int r = 0; r < 4; ++r) {
        float p = __expf(sc[nf][r] - mrow[r]);
        ps[r] += p;
        Ps[w][lg * 4 + r][nf * 16 + l15] = (bf16_t)p;
      }
#pragma unroll
    for (int off = 1; off < 16; off <<= 1)
#pragma unroll
      for (int r = 0; r < 4; ++r) ps[r] += __shfl_xor(ps[r], off);
#pragma unroll
    for (int r = 0; r < 4; ++r) lrow[r] = lrow[r] * fac[r] + ps[r];
#pragma unroll
    for (int df = 0; df < 4; ++df)
#pragma unroll
      for (int r = 0; r < 4; ++r) oacc[df][r] *= fac[r];

    // PV: O += P * V. (P is wave-private; compiler inserts lgkmcnt for RAW.)
#pragma unroll
    for (int ks = 0; ks < 2; ++ks) {
      const bf16x8 pa = *reinterpret_cast<const bf16x8*>(
          &Ps[w][l15][0] + ks * 32 + lg * 8);
#pragma unroll
      for (int df = 0; df < 4; ++df) {
        int row = df * 16 + l15;
        int byte = (row * 128 + ks * 64 + lg * 16) ^ ((row & 7) << 4);
        bf16x8 bv = *reinterpret_cast<const bf16x8*>(
            reinterpret_cast<const char*>(Vs) + byte);
        oacc[df] = __builtin_amdgcn_mfma_f32_16x16x32_bf16(pa, bv, oacc[df], 0, 0, 0);
      }
    }
    __syncthreads();
  }

  // Epilogue: normalize, store f32.
#pragma unroll
  for (int df = 0; df < 4; ++df)
#pragma unroll
    for (int r = 0; r < 4; ++r) {
      int q = q0 + w * 16 + lg * 4 + r;
      float inv = (q < len_fr && lrow[r] > 0.f) ? 1.0f / lrow[r] : 0.f;
      out[(size_t)(b * 1024 + q) * 1024 + h * 64 + df * 16 + l15] =
          oacc[df][r] * inv;
    }
}

// ---------------- launch ----------------
extern "C" void kernel_launch(void* const* d_in, const int* in_sizes, int n_in,
                              void* d_out, int out_size, void* d_ws,
                              size_t ws_size, hipStream_t stream) {
  const float* en = (const float*)d_in[0];
  const float* fr = (const float*)d_in[1];
  const int* l_en = (const int*)d_in[2];
  const int* l_fr = (const int*)d_in[3];
  const float* wq = (const float*)d_in[4];
  const float* bq = (const float*)d_in[5];
  const float* wkv = (const float*)d_in[6];
  const float* bkv = (const float*)d_in[7];
  float* out = (float*)d_out;  // output dtype is FLOAT32

  // Workspace layout (bytes):
  // wq_bf 0..2M | wkv_bf 2M..6M | Qbuf 6M..23M | Kbuf 23M..40M | Vtbuf 40M..56.6M
  // [optional] fr_bf 56.6M..73.4M | en_bf 73.4M..90.2M
  char* ws = (char*)d_ws;
  uint16_t* wq_bf = (uint16_t*)(ws);
  uint16_t* wkv_bf = (uint16_t*)(ws + 2097152);
  uint16_t* Qbuf = (uint16_t*)(ws + 6291456);
  uint16_t* Kbuf = (uint16_t*)(ws + 23068672);
  uint16_t* Vtbuf = (uint16_t*)(ws + 39845888);
  uint16_t* fr_bf = (uint16_t*)(ws + 56623104);
  uint16_t* en_bf = (uint16_t*)(ws + 73400320);
  const bool pre = ws_size >= 90177536ull;

  if (pre) {
    // Convert weights + activations to bf16 in one dispatch.
    // granules: (1M + 2M + 8.39M + 8.39M)/4 = 4,980,736 -> 19456 blocks
    cvt4_kernel<<<19456, 256, 0, stream>>>(wq, wq_bf, 1048576,
                                           wkv, wkv_bf, 2097152,
                                           fr, fr_bf, 8388608,
                                           en, en_bf, 8388608);
    gemm_fused<true><<<1536, 256, 0, stream>>>(nullptr, nullptr, fr_bf, en_bf,
                                               wq_bf, wkv_bf, bq, bkv, Qbuf,
                                               Kbuf, Vtbuf);
  } else {
    // Fallback (r7 path): weights only, A converted inside the GEMM.
    cvt4_kernel<<<3072, 256, 0, stream>>>(wq, wq_bf, 1048576,
                                          wkv, wkv_bf, 2097152,
                                          nullptr, nullptr, 0,
                                          nullptr, nullptr, 0);
    gemm_fused<false><<<1536, 256, 0, stream>>>(fr, en, nullptr, nullptr,
                                                wq_bf, wkv_bf, bq, bkv, Qbuf,
                                                Kbuf, Vtbuf);
  }

  attn_kernel<<<2048, 256, 0, stream>>>(Qbuf, Kbuf, Vtbuf, l_en, l_fr, out);
}

// Round 9
// 172.628 us; speedup vs baseline: 1.2891x; 1.0408x over previous
//
#include <hip/hip_runtime.h>
#include <hip/hip_bf16.h>
#include <stdint.h>

// Problem constants: B=8, S=1024, D=1024, H=16, DH=64
typedef __bf16 bf16_t;
typedef bf16_t bf16x8 __attribute__((ext_vector_type(8)));
typedef float f32x4 __attribute__((ext_vector_type(4)));
typedef unsigned short ushortx8 __attribute__((ext_vector_type(8)));

__device__ __forceinline__ uint16_t f2bf(float f) {
  uint32_t u = __float_as_uint(f);
  uint32_t r = u + 0x7FFFu + ((u >> 16) & 1u);  // RNE
  return (uint16_t)(r >> 16);
}

__device__ __forceinline__ int read_len(const int* __restrict__ p, int b) {
  bool is64 = (p[1] == 0) | (p[3] == 0) | (p[5] == 0) | (p[7] == 0);
  return is64 ? p[2 * b] : p[b];
}

#define GLDS16(gp, lp)                                                   \
  __builtin_amdgcn_global_load_lds(                                      \
      (const __attribute__((address_space(1))) uint32_t*)(gp),           \
      (__attribute__((address_space(3))) uint32_t*)(lp), 16, 0, 0)

// ------ merged f32 -> bf16 convert over up to 4 segments (granule = 4) ------
__global__ void cvt4_kernel(const float* __restrict__ s0, uint16_t* __restrict__ d0, int n0,
                            const float* __restrict__ s1, uint16_t* __restrict__ d1, int n1,
                            const float* __restrict__ s2, uint16_t* __restrict__ d2, int n2,
                            const float* __restrict__ s3, uint16_t* __restrict__ d3, int n3) {
  int e = (blockIdx.x * blockDim.x + threadIdx.x) * 4;
  const float* s;
  uint16_t* d;
  if (e < n0) { s = s0 + e; d = d0 + e; }
  else if ((e -= n0) < n1) { s = s1 + e; d = d1 + e; }
  else if ((e -= n1) < n2) { s = s2 + e; d = d2 + e; }
  else if ((e -= n2) < n3) { s = s3 + e; d = d3 + e; }
  else return;
  const float4 v = *reinterpret_cast<const float4*>(s);
  ushort4 o;
  o.x = f2bf(v.x); o.y = f2bf(v.y); o.z = f2bf(v.z); o.w = f2bf(v.w);
  *reinterpret_cast<ushort4*>(d) = o;
}

// -------- Fused NT GEMM: Q = fr@wq^T+bq (scaled), KV = en@wkv^T+bkv --------
// 1536 blocks, XCD-swizzled. 2-phase double-buffered pipeline:
//   iter t: STAGE(buf^1, tile t+1) -> compute(buf) -> __syncthreads (1 barrier)
// Next tile's global_load_lds fly under the MFMA phase; barrier drains residual.
// ABF16: A via global_load_lds from pre-converted bf16. Else: A f32 reg-staged
// (loads issued before compute, convert+ds_write after = T14 split).
// LDS reads XOR-swizzled byte ^= (row&7)<<4; GLDS uses pre-swizzled source.
template <bool ABF16>
__global__ __launch_bounds__(256) void gemm_fused(
    const float* __restrict__ frF, const float* __restrict__ enF,
    const uint16_t* __restrict__ frB, const uint16_t* __restrict__ enB,
    const uint16_t* __restrict__ wq, const uint16_t* __restrict__ wkv,
    const float* __restrict__ bq, const float* __restrict__ bkv,
    uint16_t* __restrict__ Qb,       // [B,H,S,DH] bf16, pre-scaled
    uint16_t* __restrict__ Kb,       // [B,H,S,DH] bf16
    uint16_t* __restrict__ Vb) {     // [B,H,DH,S] bf16
  __shared__ __attribute__((aligned(16))) uint16_t As[2][128 * 64];
  __shared__ __attribute__((aligned(16))) uint16_t Bs[2][128 * 64];
  const int t = threadIdx.x;
  const int lane = t & 63;
  const int w = t >> 6;
  const int wm = w >> 1, wn = w & 1;
  const int l15 = lane & 15, lg = lane >> 4;

  // XCD swizzle: round-robin dispatch -> contiguous logical chunk per XCD.
  const int orig = blockIdx.x;                 // 1536 = 8 * 192
  const int wgid = (orig & 7) * 192 + (orig >> 3);
  const bool isQ = wgid < 512;
  const int l = isQ ? wgid : wgid - 512;
  const int nbn_sh = isQ ? 3 : 4;              // 8 vs 16 column tiles
  const int bn = (l & ((1 << nbn_sh) - 1)) * 128;
  const int bm = (l >> nbn_sh) * 128;
  const uint16_t* Bw = isQ ? wq : wkv;
  const float* bias = isQ ? bq : bkv;
  const float scale = isQ ? 0.03125f : 1.0f;
  const uint16_t* Ab = isQ ? frB : enB;
  const float* Af = isQ ? frF : enF;

  f32x4 acc[4][4];
#pragma unroll
  for (int i = 0; i < 4; ++i)
#pragma unroll
    for (int j = 0; j < 4; ++j) acc[i][j] = (f32x4){0.f, 0.f, 0.f, 0.f};

  float4 ar0[4], ar1[4];  // f32-path register staging

  auto stageB = [&](int buf, int kt) {
#pragma unroll
    for (int i = 0; i < 4; ++i) {
      int g = t + 256 * i;            // LDS slot granule (16B units)
      int L = g ^ ((g >> 3) & 7);     // logical granule it must hold
      int row = L >> 3, k8 = L & 7;
      GLDS16(Bw + (size_t)(bn + row) * 1024 + kt + k8 * 8, &Bs[buf][g * 8]);
    }
  };
  auto stageA_bf = [&](int buf, int kt) {
#pragma unroll
    for (int i = 0; i < 4; ++i) {
      int g = t + 256 * i;
      int L = g ^ ((g >> 3) & 7);
      int row = L >> 3, k8 = L & 7;
      GLDS16(Ab + (size_t)(bm + row) * 1024 + kt + k8 * 8, &As[buf][g * 8]);
    }
  };
  auto loadA_f32 = [&](int kt) {
#pragma unroll
    for (int i = 0; i < 4; ++i) {
      int L = t + 256 * i;
      int row = L >> 3, k8 = L & 7;
      const float* src = Af + (size_t)(bm + row) * 1024 + kt + k8 * 8;
      ar0[i] = *reinterpret_cast<const float4*>(src);
      ar1[i] = *reinterpret_cast<const float4*>(src + 4);
    }
  };
  auto writeA = [&](int buf) {
#pragma unroll
    for (int i = 0; i < 4; ++i) {
      int L = t + 256 * i;
      int row = L >> 3, k8 = L & 7;
      ushortx8 o;
      o[0] = f2bf(ar0[i].x); o[1] = f2bf(ar0[i].y);
      o[2] = f2bf(ar0[i].z); o[3] = f2bf(ar0[i].w);
      o[4] = f2bf(ar1[i].x); o[5] = f2bf(ar1[i].y);
      o[6] = f2bf(ar1[i].z); o[7] = f2bf(ar1[i].w);
      int byte = (row * 128 + k8 * 16) ^ ((row & 7) << 4);
      *reinterpret_cast<ushortx8*>(reinterpret_cast<char*>(As[buf]) + byte) = o;
    }
  };
  auto compute = [&](int buf) {
#pragma unroll
    for (int ks = 0; ks < 2; ++ks) {
      const int kb = ks * 64 + lg * 16;  // byte offset within a 128B row
      bf16x8 af[4], bf[4];
#pragma unroll
      for (int mf = 0; mf < 4; ++mf) {
        int row = wm * 64 + mf * 16 + l15;
        int byte = (row * 128 + kb) ^ ((row & 7) << 4);
        af[mf] = *reinterpret_cast<const bf16x8*>(
            reinterpret_cast<const char*>(As[buf]) + byte);
      }
#pragma unroll
      for (int nf = 0; nf < 4; ++nf) {
        int row = wn * 64 + nf * 16 + l15;
        int byte = (row * 128 + kb) ^ ((row & 7) << 4);
        bf[nf] = *reinterpret_cast<const bf16x8*>(
            reinterpret_cast<const char*>(Bs[buf]) + byte);
      }
#pragma unroll
      for (int mf = 0; mf < 4; ++mf)
#pragma unroll
        for (int nf = 0; nf < 4; ++nf)
          acc[mf][nf] = __builtin_amdgcn_mfma_f32_16x16x32_bf16(
              af[mf], bf[nf], acc[mf][nf], 0, 0, 0);
    }
  };

  // ---- prologue: fill buffer 0 with tile 0 ----
  if (ABF16) {
    stageB(0, 0);
    stageA_bf(0, 0);
  } else {
    loadA_f32(0);
    stageB(0, 0);
    writeA(0);
  }
  __syncthreads();  // drains vmcnt+lgkm: tile 0 resident

  // ---- 2-phase main loop: one barrier per K-step ----
#pragma unroll 2
  for (int tt = 0; tt < 16; ++tt) {
    const int cur = tt & 1;
    const int ktn = (tt + 1) * 64;
    if (ABF16) {
      if (tt < 15) { stageB(cur ^ 1, ktn); stageA_bf(cur ^ 1, ktn); }
      compute(cur);
    } else {
      if (tt < 15) { stageB(cur ^ 1, ktn); loadA_f32(ktn); }
      compute(cur);
      if (tt < 15) writeA(cur ^ 1);  // T14: convert+write after compute
    }
    __syncthreads();
  }

  // Epilogue: add bias, scale, scatter bf16 to attention layouts.
#pragma unroll
  for (int mf = 0; mf < 4; ++mf) {
#pragma unroll
    for (int nf = 0; nf < 4; ++nf) {
      int n = bn + wn * 64 + nf * 16 + l15;
      float bv = bias[n];
#pragma unroll
      for (int r = 0; r < 4; ++r) {
        int m = bm + wm * 64 + mf * 16 + lg * 4 + r;
        float v = (acc[mf][nf][r] + bv) * scale;
        uint16_t o = f2bf(v);
        int b = m >> 10, s = m & 1023;
        if (isQ) {
          int h = n >> 6, d = n & 63;
          Qb[((((b * 16 + h) << 10) | s) << 6) | d] = o;
        } else if (n < 1024) {
          int h = n >> 6, d = n & 63;
          Kb[((((b * 16 + h) << 10) | s) << 6) | d] = o;
        } else {
          int n2 = n - 1024;
          int h = n2 >> 6, d = n2 & 63;
          Vb[((((b * 16 + h) << 6) | d) << 10) | s] = o;
        }
      }
    }
  }
}

// ---------------- Flash attention ----------------
// 1D grid 2048 blocks (XCD-swizzled), 256 threads = 4 waves, 16 q-rows each.
__global__ __launch_bounds__(256) void attn_kernel(
    const uint16_t* __restrict__ Qb,  // [B,H,S,DH] bf16, pre-scaled
    const uint16_t* __restrict__ Kb,  // [B,H,S,DH] bf16
    const uint16_t* __restrict__ Vt,  // [B,H,DH,S] bf16
    const int* __restrict__ l_en_p, const int* __restrict__ l_fr_p,
    float* __restrict__ out) {        // [B,S,D] f32
  __shared__ __attribute__((aligned(16))) uint16_t Ks[64 * 64];
  __shared__ __attribute__((aligned(16))) uint16_t Vs[64 * 64];
  __shared__ __attribute__((aligned(16))) bf16_t Ps[4][16][72];
  const int t = threadIdx.x;
  const int lane = t & 63, w = t >> 6;
  const int l15 = lane & 15, lg = lane >> 4;
  // XCD swizzle: each XCD owns 16 consecutive heads (K/V locality).
  const int orig = blockIdx.x;                 // 2048 = 8 * 256
  const int wgid = (orig & 7) * 256 + (orig >> 3);
  const int bh = wgid >> 4;
  const int q0 = (wgid & 15) << 6;
  const int b = bh >> 4, h = bh & 15;
  const int len_en = read_len(l_en_p, b);
  const int len_fr = read_len(l_fr_p, b);

  if (q0 >= len_fr) {
    for (int i = t; i < 64 * 64; i += 256) {
      int rr = i >> 6, cc = i & 63;
      out[(size_t)(b * 1024 + q0 + rr) * 1024 + h * 64 + cc] = 0.f;
    }
    return;
  }

  // Hoist this wave's Q fragments (16 rows x 64) into registers.
  const uint16_t* qbase =
      Qb + ((size_t)bh * 1024 + q0 + w * 16 + l15) * 64 + lg * 8;
  const bf16x8 aq0 = *reinterpret_cast<const bf16x8*>(qbase);
  const bf16x8 aq1 = *reinterpret_cast<const bf16x8*>(qbase + 32);

  float mrow[4], lrow[4];
  f32x4 oacc[4];
#pragma unroll
  for (int r = 0; r < 4; ++r) { mrow[r] = -1e30f; lrow[r] = 0.f; }
#pragma unroll
  for (int df = 0; df < 4; ++df) oacc[df] = (f32x4){0.f, 0.f, 0.f, 0.f};

  const int ntiles = (len_en + 63) >> 6;
  for (int tt = 0; tt < ntiles; ++tt) {
    const int j0 = tt * 64;
    // Stage K tile [64 j][64 d] and V tile [64 d][64 j] via GLDS,
    // linear LDS dest + swizzled global source.
#pragma unroll
    for (int i = 0; i < 2; ++i) {
      int g = t + 256 * i;
      int L = g ^ ((g >> 3) & 7);
      int row = L >> 3, k8 = L & 7;
      GLDS16(Kb + ((size_t)bh * 1024 + j0 + row) * 64 + k8 * 8, Ks + g * 8);
      GLDS16(Vt + ((size_t)bh * 64 + row) * 1024 + j0 + k8 * 8, Vs + g * 8);
    }
    __syncthreads();

    // Scores: S = Q * K^T  (16x64 per wave), f32.
    f32x4 sc[4];
#pragma unroll
    for (int nf = 0; nf < 4; ++nf) sc[nf] = (f32x4){0.f, 0.f, 0.f, 0.f};
#pragma unroll
    for (int ks = 0; ks < 2; ++ks) {
      const bf16x8 aq = ks ? aq1 : aq0;
      const int kb = ks * 64 + lg * 16;
#pragma unroll
      for (int nf = 0; nf < 4; ++nf) {
        int row = nf * 16 + l15;
        int byte = (row * 128 + kb) ^ ((row & 7) << 4);
        bf16x8 bk = *reinterpret_cast<const bf16x8*>(
            reinterpret_cast<const char*>(Ks) + byte);
        sc[nf] = __builtin_amdgcn_mfma_f32_16x16x32_bf16(aq, bk, sc[nf], 0, 0, 0);
      }
    }
    // Key mask.
#pragma unroll
    for (int nf = 0; nf < 4; ++nf) {
      int col = j0 + nf * 16 + l15;
      if (col >= len_en) sc[nf] = (f32x4){-1e30f, -1e30f, -1e30f, -1e30f};
    }
    // Row max.
    float tm[4];
#pragma unroll
    for (int r = 0; r < 4; ++r)
      tm[r] = fmaxf(fmaxf(sc[0][r], sc[1][r]), fmaxf(sc[2][r], sc[3][r]));
#pragma unroll
    for (int off = 1; off < 16; off <<= 1)
#pragma unroll
      for (int r = 0; r < 4; ++r) tm[r] = fmaxf(tm[r], __shfl_xor(tm[r], off));

    float fac[4];
#pragma unroll
    for (int r = 0; r < 4; ++r) {
      float mn = fmaxf(mrow[r], tm[r]);
      fac[r] = __expf(mrow[r] - mn);
      mrow[r] = mn;
    }
    // P = exp(S - m), row sums, write P to LDS (wave-private) for transpose.
    float ps[4] = {0.f, 0.f, 0.f, 0.f};
#pragma unroll
    for (int nf = 0; nf < 4; ++nf)
#pragma unroll
      for (int r = 0; r < 4; ++r) {
        float p = __expf(sc[nf][r] - mrow[r]);
        ps[r] += p;
        Ps[w][lg * 4 + r][nf * 16 + l15] = (bf16_t)p;
      }
#pragma unroll
    for (int off = 1; off < 16; off <<= 1)
#pragma unroll
      for (int r = 0; r < 4; ++r) ps[r] += __shfl_xor(ps[r], off);
#pragma unroll
    for (int r = 0; r < 4; ++r) lrow[r] = lrow[r] * fac[r] + ps[r];
#pragma unroll
    for (int df = 0; df < 4; ++df)
#pragma unroll
      for (int r = 0; r < 4; ++r) oacc[df][r] *= fac[r];

    // PV: O += P * V. (P is wave-private; compiler inserts lgkmcnt for RAW.)
#pragma unroll
    for (int ks = 0; ks < 2; ++ks) {
      const bf16x8 pa = *reinterpret_cast<const bf16x8*>(
          &Ps[w][l15][0] + ks * 32 + lg * 8);
#pragma unroll
      for (int df = 0; df < 4; ++df) {
        int row = df * 16 + l15;
        int byte = (row * 128 + ks * 64 + lg * 16) ^ ((row & 7) << 4);
        bf16x8 bv = *reinterpret_cast<const bf16x8*>(
            reinterpret_cast<const char*>(Vs) + byte);
        oacc[df] = __builtin_amdgcn_mfma_f32_16x16x32_bf16(pa, bv, oacc[df], 0, 0, 0);
      }
    }
    __syncthreads();
  }

  // Epilogue: normalize, store f32.
#pragma unroll
  for (int df = 0; df < 4; ++df)
#pragma unroll
    for (int r = 0; r < 4; ++r) {
      int q = q0 + w * 16 + lg * 4 + r;
      float inv = (q < len_fr && lrow[r] > 0.f) ? 1.0f / lrow[r] : 0.f;
      out[(size_t)(b * 1024 + q) * 1024 + h * 64 + df * 16 + l15] =
          oacc[df][r] * inv;
    }
}

// ---------------- launch ----------------
extern "C" void kernel_launch(void* const* d_in, const int* in_sizes, int n_in,
                              void* d_out, int out_size, void* d_ws,
                              size_t ws_size, hipStream_t stream) {
  const float* en = (const float*)d_in[0];
  const float* fr = (const float*)d_in[1];
  const int* l_en = (const int*)d_in[2];
  const int* l_fr = (const int*)d_in[3];
  const float* wq = (const float*)d_in[4];
  const float* bq = (const float*)d_in[5];
  const float* wkv = (const float*)d_in[6];
  const float* bkv = (const float*)d_in[7];
  float* out = (float*)d_out;  // output dtype is FLOAT32

  // Workspace layout (bytes):
  // wq_bf 0..2M | wkv_bf 2M..6M | Qbuf 6M..23M | Kbuf 23M..40M | Vtbuf 40M..56.6M
  // [optional] fr_bf 56.6M..73.4M | en_bf 73.4M..90.2M
  char* ws = (char*)d_ws;
  uint16_t* wq_bf = (uint16_t*)(ws);
  uint16_t* wkv_bf = (uint16_t*)(ws + 2097152);
  uint16_t* Qbuf = (uint16_t*)(ws + 6291456);
  uint16_t* Kbuf = (uint16_t*)(ws + 23068672);
  uint16_t* Vtbuf = (uint16_t*)(ws + 39845888);
  uint16_t* fr_bf = (uint16_t*)(ws + 56623104);
  uint16_t* en_bf = (uint16_t*)(ws + 73400320);
  const bool pre = ws_size >= 90177536ull;

  if (pre) {
    cvt4_kernel<<<19456, 256, 0, stream>>>(wq, wq_bf, 1048576,
                                           wkv, wkv_bf, 2097152,
                                           fr, fr_bf, 8388608,
                                           en, en_bf, 8388608);
    gemm_fused<true><<<1536, 256, 0, stream>>>(nullptr, nullptr, fr_bf, en_bf,
                                               wq_bf, wkv_bf, bq, bkv, Qbuf,
                                               Kbuf, Vtbuf);
  } else {
    cvt4_kernel<<<3072, 256, 0, stream>>>(wq, wq_bf, 1048576,
                                          wkv, wkv_bf, 2097152,
                                          nullptr, nullptr, 0,
                                          nullptr, nullptr, 0);
    gemm_fused<false><<<1536, 256, 0, stream>>>(fr, en, nullptr, nullptr,
                                                wq_bf, wkv_bf, bq, bkv, Qbuf,
                                                Kbuf, Vtbuf);
  }

  attn_kernel<<<2048, 256, 0, stream>>>(Qbuf, Kbuf, Vtbuf, l_en, l_fr, out);
}

// Round 10
// 142.782 us; speedup vs baseline: 1.5586x; 1.2090x over previous
//
#include <hip/hip_runtime.h>
#include <hip/hip_bf16.h>
#include <stdint.h>

// Problem constants: B=8, S=1024, D=1024, H=16, DH=64
typedef __bf16 bf16_t;
typedef bf16_t bf16x8 __attribute__((ext_vector_type(8)));
typedef float f32x4 __attribute__((ext_vector_type(4)));
typedef unsigned short ushortx8 __attribute__((ext_vector_type(8)));

__device__ __forceinline__ uint16_t f2bf(float f) {
  uint32_t u = __float_as_uint(f);
  uint32_t r = u + 0x7FFFu + ((u >> 16) & 1u);  // RNE
  return (uint16_t)(r >> 16);
}

__device__ __forceinline__ int read_len(const int* __restrict__ p, int b) {
  bool is64 = (p[1] == 0) | (p[3] == 0) | (p[5] == 0) | (p[7] == 0);
  return is64 ? p[2 * b] : p[b];
}

#define GLDS16(gp, lp)                                                   \
  __builtin_amdgcn_global_load_lds(                                      \
      (const __attribute__((address_space(1))) uint32_t*)(gp),           \
      (__attribute__((address_space(3))) uint32_t*)(lp), 16, 0, 0)

// ------ merged f32 -> bf16 convert over up to 4 segments (granule = 4) ------
// Segments 2/3 ([B,S,D] activations) are length-masked: rows >= ceil128(len)
// are never read downstream (only live 128-row GEMM tiles read them).
__global__ void cvt4_kernel(const float* __restrict__ s0, uint16_t* __restrict__ d0, int n0,
                            const float* __restrict__ s1, uint16_t* __restrict__ d1, int n1,
                            const float* __restrict__ s2, uint16_t* __restrict__ d2, int n2,
                            const float* __restrict__ s3, uint16_t* __restrict__ d3, int n3,
                            const int* __restrict__ msk2, const int* __restrict__ msk3) {
  int e = (blockIdx.x * blockDim.x + threadIdx.x) * 4;
  const float* s;
  uint16_t* d;
  const int* msk = nullptr;
  if (e < n0) { s = s0 + e; d = d0 + e; }
  else if ((e -= n0) < n1) { s = s1 + e; d = d1 + e; }
  else if ((e -= n1) < n2) { s = s2 + e; d = d2 + e; msk = msk2; }
  else if ((e -= n2) < n3) { s = s3 + e; d = d3 + e; msk = msk3; }
  else return;
  if (msk) {
    int row = (e >> 10) & 1023, b = e >> 20;   // 1024 elems/row, 1M elems/batch
    int need = (read_len(msk, b) + 127) & ~127;
    if (row >= need) return;
  }
  const float4 v = *reinterpret_cast<const float4*>(s);
  ushort4 o;
  o.x = f2bf(v.x); o.y = f2bf(v.y); o.z = f2bf(v.z); o.w = f2bf(v.w);
  *reinterpret_cast<ushort4*>(d) = o;
}

// -------- Fused NT GEMM: Q = fr@wq^T+bq (scaled), KV = en@wkv^T+bkv --------
// 1536 blocks, XCD-swizzled, 2-phase double-buffered (r9). Length-aware:
// m-tiles entirely beyond len_fr (Q) / len_en (KV) are never read by the
// attention kernel (masked rows contribute exactly 0 there) -> early exit.
template <bool ABF16>
__global__ __launch_bounds__(256) void gemm_fused(
    const float* __restrict__ frF, const float* __restrict__ enF,
    const uint16_t* __restrict__ frB, const uint16_t* __restrict__ enB,
    const uint16_t* __restrict__ wq, const uint16_t* __restrict__ wkv,
    const float* __restrict__ bq, const float* __restrict__ bkv,
    const int* __restrict__ l_en_p, const int* __restrict__ l_fr_p,
    uint16_t* __restrict__ Qb,       // [B,H,S,DH] bf16, pre-scaled
    uint16_t* __restrict__ Kb,       // [B,H,S,DH] bf16
    uint16_t* __restrict__ Vb) {     // [B,H,DH,S] bf16
  __shared__ __attribute__((aligned(16))) uint16_t As[2][128 * 64];
  __shared__ __attribute__((aligned(16))) uint16_t Bs[2][128 * 64];
  const int t = threadIdx.x;
  const int lane = t & 63;
  const int w = t >> 6;
  const int wm = w >> 1, wn = w & 1;
  const int l15 = lane & 15, lg = lane >> 4;

  // XCD swizzle: round-robin dispatch -> contiguous logical chunk per XCD.
  const int orig = blockIdx.x;                 // 1536 = 8 * 192
  const int wgid = (orig & 7) * 192 + (orig >> 3);
  const bool isQ = wgid < 512;
  const int l = isQ ? wgid : wgid - 512;
  const int nbn_sh = isQ ? 3 : 4;              // 8 vs 16 column tiles
  const int bn = (l & ((1 << nbn_sh) - 1)) * 128;
  const int bm = (l >> nbn_sh) * 128;

  // Length-aware early exit: this m-tile's outputs are never consumed.
  const int mb = bm >> 10;                     // batch of this m-tile
  const int need = isQ ? read_len(l_fr_p, mb) : read_len(l_en_p, mb);
  if ((bm & 1023) >= need) return;

  const uint16_t* Bw = isQ ? wq : wkv;
  const float* bias = isQ ? bq : bkv;
  const float scale = isQ ? 0.03125f : 1.0f;
  const uint16_t* Ab = isQ ? frB : enB;
  const float* Af = isQ ? frF : enF;

  f32x4 acc[4][4];
#pragma unroll
  for (int i = 0; i < 4; ++i)
#pragma unroll
    for (int j = 0; j < 4; ++j) acc[i][j] = (f32x4){0.f, 0.f, 0.f, 0.f};

  float4 ar0[4], ar1[4];  // f32-path register staging

  auto stageB = [&](int buf, int kt) {
#pragma unroll
    for (int i = 0; i < 4; ++i) {
      int g = t + 256 * i;            // LDS slot granule (16B units)
      int L = g ^ ((g >> 3) & 7);     // logical granule it must hold
      int row = L >> 3, k8 = L & 7;
      GLDS16(Bw + (size_t)(bn + row) * 1024 + kt + k8 * 8, &Bs[buf][g * 8]);
    }
  };
  auto stageA_bf = [&](int buf, int kt) {
#pragma unroll
    for (int i = 0; i < 4; ++i) {
      int g = t + 256 * i;
      int L = g ^ ((g >> 3) & 7);
      int row = L >> 3, k8 = L & 7;
      GLDS16(Ab + (size_t)(bm + row) * 1024 + kt + k8 * 8, &As[buf][g * 8]);
    }
  };
  auto loadA_f32 = [&](int kt) {
#pragma unroll
    for (int i = 0; i < 4; ++i) {
      int L = t + 256 * i;
      int row = L >> 3, k8 = L & 7;
      const float* src = Af + (size_t)(bm + row) * 1024 + kt + k8 * 8;
      ar0[i] = *reinterpret_cast<const float4*>(src);
      ar1[i] = *reinterpret_cast<const float4*>(src + 4);
    }
  };
  auto writeA = [&](int buf) {
#pragma unroll
    for (int i = 0; i < 4; ++i) {
      int L = t + 256 * i;
      int row = L >> 3, k8 = L & 7;
      ushortx8 o;
      o[0] = f2bf(ar0[i].x); o[1] = f2bf(ar0[i].y);
      o[2] = f2bf(ar0[i].z); o[3] = f2bf(ar0[i].w);
      o[4] = f2bf(ar1[i].x); o[5] = f2bf(ar1[i].y);
      o[6] = f2bf(ar1[i].z); o[7] = f2bf(ar1[i].w);
      int byte = (row * 128 + k8 * 16) ^ ((row & 7) << 4);
      *reinterpret_cast<ushortx8*>(reinterpret_cast<char*>(As[buf]) + byte) = o;
    }
  };
  auto compute = [&](int buf) {
#pragma unroll
    for (int ks = 0; ks < 2; ++ks) {
      const int kb = ks * 64 + lg * 16;  // byte offset within a 128B row
      bf16x8 af[4], bf[4];
#pragma unroll
      for (int mf = 0; mf < 4; ++mf) {
        int row = wm * 64 + mf * 16 + l15;
        int byte = (row * 128 + kb) ^ ((row & 7) << 4);
        af[mf] = *reinterpret_cast<const bf16x8*>(
            reinterpret_cast<const char*>(As[buf]) + byte);
      }
#pragma unroll
      for (int nf = 0; nf < 4; ++nf) {
        int row = wn * 64 + nf * 16 + l15;
        int byte = (row * 128 + kb) ^ ((row & 7) << 4);
        bf[nf] = *reinterpret_cast<const bf16x8*>(
            reinterpret_cast<const char*>(Bs[buf]) + byte);
      }
#pragma unroll
      for (int mf = 0; mf < 4; ++mf)
#pragma unroll
        for (int nf = 0; nf < 4; ++nf)
          acc[mf][nf] = __builtin_amdgcn_mfma_f32_16x16x32_bf16(
              af[mf], bf[nf], acc[mf][nf], 0, 0, 0);
    }
  };

  // ---- prologue: fill buffer 0 with tile 0 ----
  if (ABF16) {
    stageB(0, 0);
    stageA_bf(0, 0);
  } else {
    loadA_f32(0);
    stageB(0, 0);
    writeA(0);
  }
  __syncthreads();  // drains vmcnt+lgkm: tile 0 resident

  // ---- 2-phase main loop: one barrier per K-step ----
#pragma unroll 2
  for (int tt = 0; tt < 16; ++tt) {
    const int cur = tt & 1;
    const int ktn = (tt + 1) * 64;
    if (ABF16) {
      if (tt < 15) { stageB(cur ^ 1, ktn); stageA_bf(cur ^ 1, ktn); }
      compute(cur);
    } else {
      if (tt < 15) { stageB(cur ^ 1, ktn); loadA_f32(ktn); }
      compute(cur);
      if (tt < 15) writeA(cur ^ 1);  // T14: convert+write after compute
    }
    __syncthreads();
  }

  // Epilogue: add bias, scale, scatter bf16 to attention layouts.
#pragma unroll
  for (int mf = 0; mf < 4; ++mf) {
#pragma unroll
    for (int nf = 0; nf < 4; ++nf) {
      int n = bn + wn * 64 + nf * 16 + l15;
      float bv = bias[n];
#pragma unroll
      for (int r = 0; r < 4; ++r) {
        int m = bm + wm * 64 + mf * 16 + lg * 4 + r;
        float v = (acc[mf][nf][r] + bv) * scale;
        uint16_t o = f2bf(v);
        int b = m >> 10, s = m & 1023;
        if (isQ) {
          int h = n >> 6, d = n & 63;
          Qb[((((b * 16 + h) << 10) | s) << 6) | d] = o;
        } else if (n < 1024) {
          int h = n >> 6, d = n & 63;
          Kb[((((b * 16 + h) << 10) | s) << 6) | d] = o;
        } else {
          int n2 = n - 1024;
          int h = n2 >> 6, d = n2 & 63;
          Vb[((((b * 16 + h) << 6) | d) << 10) | s] = o;
        }
      }
    }
  }
}

// ---------------- Flash attention ----------------
// 1D grid 2048 blocks (XCD-swizzled), 256 threads = 4 waves, 16 q-rows each.
__global__ __launch_bounds__(256) void attn_kernel(
    const uint16_t* __restrict__ Qb,  // [B,H,S,DH] bf16, pre-scaled
    const uint16_t* __restrict__ Kb,  // [B,H,S,DH] bf16
    const uint16_t* __restrict__ Vt,  // [B,H,DH,S] bf16
    const int* __restrict__ l_en_p, const int* __restrict__ l_fr_p,
    float* __restrict__ out) {        // [B,S,D] f32
  __shared__ __attribute__((aligned(16))) uint16_t Ks[64 * 64];
  __shared__ __attribute__((aligned(16))) uint16_t Vs[64 * 64];
  __shared__ __attribute__((aligned(16))) bf16_t Ps[4][16][72];
  const int t = threadIdx.x;
  const int lane = t & 63, w = t >> 6;
  const int l15 = lane & 15, lg = lane >> 4;
  // XCD swizzle: each XCD owns 16 consecutive heads (K/V locality).
  const int orig = blockIdx.x;                 // 2048 = 8 * 256
  const int wgid = (orig & 7) * 256 + (orig >> 3);
  const int bh = wgid >> 4;
  const int q0 = (wgid & 15) << 6;
  const int b = bh >> 4, h = bh & 15;
  const int len_en = read_len(l_en_p, b);
  const int len_fr = read_len(l_fr_p, b);

  if (q0 >= len_fr) {
    for (int i = t; i < 64 * 64; i += 256) {
      int rr = i >> 6, cc = i & 63;
      out[(size_t)(b * 1024 + q0 + rr) * 1024 + h * 64 + cc] = 0.f;
    }
    return;
  }

  // Hoist this wave's Q fragments (16 rows x 64) into registers.
  const uint16_t* qbase =
      Qb + ((size_t)bh * 1024 + q0 + w * 16 + l15) * 64 + lg * 8;
  const bf16x8 aq0 = *reinterpret_cast<const bf16x8*>(qbase);
  const bf16x8 aq1 = *reinterpret_cast<const bf16x8*>(qbase + 32);

  float mrow[4], lrow[4];
  f32x4 oacc[4];
#pragma unroll
  for (int r = 0; r < 4; ++r) { mrow[r] = -1e30f; lrow[r] = 0.f; }
#pragma unroll
  for (int df = 0; df < 4; ++df) oacc[df] = (f32x4){0.f, 0.f, 0.f, 0.f};

  const int ntiles = (len_en + 63) >> 6;
  for (int tt = 0; tt < ntiles; ++tt) {
    const int j0 = tt * 64;
    // Stage K tile [64 j][64 d] and V tile [64 d][64 j] via GLDS,
    // linear LDS dest + swizzled global source.
#pragma unroll
    for (int i = 0; i < 2; ++i) {
      int g = t + 256 * i;
      int L = g ^ ((g >> 3) & 7);
      int row = L >> 3, k8 = L & 7;
      GLDS16(Kb + ((size_t)bh * 1024 + j0 + row) * 64 + k8 * 8, Ks + g * 8);
      GLDS16(Vt + ((size_t)bh * 64 + row) * 1024 + j0 + k8 * 8, Vs + g * 8);
    }
    __syncthreads();

    // Scores: S = Q * K^T  (16x64 per wave), f32.
    f32x4 sc[4];
#pragma unroll
    for (int nf = 0; nf < 4; ++nf) sc[nf] = (f32x4){0.f, 0.f, 0.f, 0.f};
#pragma unroll
    for (int ks = 0; ks < 2; ++ks) {
      const bf16x8 aq = ks ? aq1 : aq0;
      const int kb = ks * 64 + lg * 16;
#pragma unroll
      for (int nf = 0; nf < 4; ++nf) {
        int row = nf * 16 + l15;
        int byte = (row * 128 + kb) ^ ((row & 7) << 4);
        bf16x8 bk = *reinterpret_cast<const bf16x8*>(
            reinterpret_cast<const char*>(Ks) + byte);
        sc[nf] = __builtin_amdgcn_mfma_f32_16x16x32_bf16(aq, bk, sc[nf], 0, 0, 0);
      }
    }
    // Key mask.
#pragma unroll
    for (int nf = 0; nf < 4; ++nf) {
      int col = j0 + nf * 16 + l15;
      if (col >= len_en) sc[nf] = (f32x4){-1e30f, -1e30f, -1e30f, -1e30f};
    }
    // Row max.
    float tm[4];
#pragma unroll
    for (int r = 0; r < 4; ++r)
      tm[r] = fmaxf(fmaxf(sc[0][r], sc[1][r]), fmaxf(sc[2][r], sc[3][r]));
#pragma unroll
    for (int off = 1; off < 16; off <<= 1)
#pragma unroll
      for (int r = 0; r < 4; ++r) tm[r] = fmaxf(tm[r], __shfl_xor(tm[r], off));

    float fac[4];
#pragma unroll
    for (int r = 0; r < 4; ++r) {
      float mn = fmaxf(mrow[r], tm[r]);
      fac[r] = __expf(mrow[r] - mn);
      mrow[r] = mn;
    }
    // P = exp(S - m), row sums, write P to LDS (wave-private) for transpose.
    float ps[4] = {0.f, 0.f, 0.f, 0.f};
#pragma unroll
    for (int nf = 0; nf < 4; ++nf)
#pragma unroll
      for (int r = 0; r < 4; ++r) {
        float p = __expf(sc[nf][r] - mrow[r]);
        ps[r] += p;
        Ps[w][lg * 4 + r][nf * 16 + l15] = (bf16_t)p;
      }
#pragma unroll
    for (int off = 1; off < 16; off <<= 1)
#pragma unroll
      for (int r = 0; r < 4; ++r) ps[r] += __shfl_xor(ps[r], off);
#pragma unroll
    for (int r = 0; r < 4; ++r) lrow[r] = lrow[r] * fac[r] + ps[r];
#pragma unroll
    for (int df = 0; df < 4; ++df)
#pragma unroll
      for (int r = 0; r < 4; ++r) oacc[df][r] *= fac[r];

    // PV: O += P * V. (P is wave-private; compiler inserts lgkmcnt for RAW.)
#pragma unroll
    for (int ks = 0; ks < 2; ++ks) {
      const bf16x8 pa = *reinterpret_cast<const bf16x8*>(
          &Ps[w][l15][0] + ks * 32 + lg * 8);
#pragma unroll
      for (int df = 0; df < 4; ++df) {
        int row = df * 16 + l15;
        int byte = (row * 128 + ks * 64 + lg * 16) ^ ((row & 7) << 4);
        bf16x8 bv = *reinterpret_cast<const bf16x8*>(
            reinterpret_cast<const char*>(Vs) + byte);
        oacc[df] = __builtin_amdgcn_mfma_f32_16x16x32_bf16(pa, bv, oacc[df], 0, 0, 0);
      }
    }
    __syncthreads();
  }

  // Epilogue: normalize, store f32.
#pragma unroll
  for (int df = 0; df < 4; ++df)
#pragma unroll
    for (int r = 0; r < 4; ++r) {
      int q = q0 + w * 16 + lg * 4 + r;
      float inv = (q < len_fr && lrow[r] > 0.f) ? 1.0f / lrow[r] : 0.f;
      out[(size_t)(b * 1024 + q) * 1024 + h * 64 + df * 16 + l15] =
          oacc[df][r] * inv;
    }
}

// ---------------- launch ----------------
extern "C" void kernel_launch(void* const* d_in, const int* in_sizes, int n_in,
                              void* d_out, int out_size, void* d_ws,
                              size_t ws_size, hipStream_t stream) {
  const float* en = (const float*)d_in[0];
  const float* fr = (const float*)d_in[1];
  const int* l_en = (const int*)d_in[2];
  const int* l_fr = (const int*)d_in[3];
  const float* wq = (const float*)d_in[4];
  const float* bq = (const float*)d_in[5];
  const float* wkv = (const float*)d_in[6];
  const float* bkv = (const float*)d_in[7];
  float* out = (float*)d_out;  // output dtype is FLOAT32

  // Workspace layout (bytes):
  // wq_bf 0..2M | wkv_bf 2M..6M | Qbuf 6M..23M | Kbuf 23M..40M | Vtbuf 40M..56.6M
  // [optional] fr_bf 56.6M..73.4M | en_bf 73.4M..90.2M
  char* ws = (char*)d_ws;
  uint16_t* wq_bf = (uint16_t*)(ws);
  uint16_t* wkv_bf = (uint16_t*)(ws + 2097152);
  uint16_t* Qbuf = (uint16_t*)(ws + 6291456);
  uint16_t* Kbuf = (uint16_t*)(ws + 23068672);
  uint16_t* Vtbuf = (uint16_t*)(ws + 39845888);
  uint16_t* fr_bf = (uint16_t*)(ws + 56623104);
  uint16_t* en_bf = (uint16_t*)(ws + 73400320);
  const bool pre = ws_size >= 90177536ull;

  if (pre) {
    cvt4_kernel<<<19456, 256, 0, stream>>>(wq, wq_bf, 1048576,
                                           wkv, wkv_bf, 2097152,
                                           fr, fr_bf, 8388608,
                                           en, en_bf, 8388608,
                                           l_fr, l_en);
    gemm_fused<true><<<1536, 256, 0, stream>>>(nullptr, nullptr, fr_bf, en_bf,
                                               wq_bf, wkv_bf, bq, bkv,
                                               l_en, l_fr, Qbuf, Kbuf, Vtbuf);
  } else {
    cvt4_kernel<<<3072, 256, 0, stream>>>(wq, wq_bf, 1048576,
                                          wkv, wkv_bf, 2097152,
                                          nullptr, nullptr, 0,
                                          nullptr, nullptr, 0,
                                          nullptr, nullptr);
    gemm_fused<false><<<1536, 256, 0, stream>>>(fr, en, nullptr, nullptr,
                                                wq_bf, wkv_bf, bq, bkv,
                                                l_en, l_fr, Qbuf, Kbuf, Vtbuf);
  }

  attn_kernel<<<2048, 256, 0, stream>>>(Qbuf, Kbuf, Vtbuf, l_en, l_fr, out);
}

// Round 11
// 134.988 us; speedup vs baseline: 1.6486x; 1.0577x over previous
//
#include <hip/hip_runtime.h>
#include <hip/hip_bf16.h>
#include <stdint.h>

// Problem constants: B=8, S=1024, D=1024, H=16, DH=64
typedef __bf16 bf16_t;
typedef bf16_t bf16x8 __attribute__((ext_vector_type(8)));
typedef float f32x4 __attribute__((ext_vector_type(4)));
typedef unsigned short ushortx8 __attribute__((ext_vector_type(8)));

__device__ __forceinline__ uint16_t f2bf(float f) {
  uint32_t u = __float_as_uint(f);
  uint32_t r = u + 0x7FFFu + ((u >> 16) & 1u);  // RNE
  return (uint16_t)(r >> 16);
}

__device__ __forceinline__ int read_len(const int* __restrict__ p, int b) {
  bool is64 = (p[1] == 0) | (p[3] == 0) | (p[5] == 0) | (p[7] == 0);
  return is64 ? p[2 * b] : p[b];
}

#define GLDS16(gp, lp)                                                   \
  __builtin_amdgcn_global_load_lds(                                      \
      (const __attribute__((address_space(1))) uint32_t*)(gp),           \
      (__attribute__((address_space(3))) uint32_t*)(lp), 16, 0, 0)

// ------ merged f32 -> bf16 convert over up to 4 segments (granule = 4) ------
// Segments 2/3 ([B,S,D] activations) are length-masked: rows >= ceil128(len)
// are never read downstream (only live 128-row GEMM tiles read them).
__global__ void cvt4_kernel(const float* __restrict__ s0, uint16_t* __restrict__ d0, int n0,
                            const float* __restrict__ s1, uint16_t* __restrict__ d1, int n1,
                            const float* __restrict__ s2, uint16_t* __restrict__ d2, int n2,
                            const float* __restrict__ s3, uint16_t* __restrict__ d3, int n3,
                            const int* __restrict__ msk2, const int* __restrict__ msk3) {
  int e = (blockIdx.x * blockDim.x + threadIdx.x) * 4;
  const float* s;
  uint16_t* d;
  const int* msk = nullptr;
  if (e < n0) { s = s0 + e; d = d0 + e; }
  else if ((e -= n0) < n1) { s = s1 + e; d = d1 + e; }
  else if ((e -= n1) < n2) { s = s2 + e; d = d2 + e; msk = msk2; }
  else if ((e -= n2) < n3) { s = s3 + e; d = d3 + e; msk = msk3; }
  else return;
  if (msk) {
    int row = (e >> 10) & 1023, b = e >> 20;   // 1024 elems/row, 1M elems/batch
    int need = (read_len(msk, b) + 127) & ~127;
    if (row >= need) return;
  }
  const float4 v = *reinterpret_cast<const float4*>(s);
  ushort4 o;
  o.x = f2bf(v.x); o.y = f2bf(v.y); o.z = f2bf(v.z); o.w = f2bf(v.w);
  *reinterpret_cast<ushort4*>(d) = o;
}

// -------- Fused NT GEMM: Q = fr@wq^T+bq (scaled), KV = en@wkv^T+bkv --------
// 1536 blocks. Balanced XCD mapping: unit (matrix, batch b, m-tile i) lands on
// XCD (b+i)&7, so each XCD gets one m-tile per batch per matrix -> live-tile
// count per XCD ~uniform for any length distribution. bn fastest within unit.
// 2-phase double-buffered pipeline (r9); length-aware early exit (r10).
template <bool ABF16>
__global__ __launch_bounds__(256) void gemm_fused(
    const float* __restrict__ frF, const float* __restrict__ enF,
    const uint16_t* __restrict__ frB, const uint16_t* __restrict__ enB,
    const uint16_t* __restrict__ wq, const uint16_t* __restrict__ wkv,
    const float* __restrict__ bq, const float* __restrict__ bkv,
    const int* __restrict__ l_en_p, const int* __restrict__ l_fr_p,
    uint16_t* __restrict__ Qb,       // [B,H,S,DH] bf16, pre-scaled
    uint16_t* __restrict__ Kb,       // [B,H,S,DH] bf16
    uint16_t* __restrict__ Vb) {     // [B,H,DH,S] bf16
  __shared__ __attribute__((aligned(16))) uint16_t As[2][128 * 64];
  __shared__ __attribute__((aligned(16))) uint16_t Bs[2][128 * 64];
  const int t = threadIdx.x;
  const int lane = t & 63;
  const int w = t >> 6;
  const int wm = w >> 1, wn = w & 1;
  const int l15 = lane & 15, lg = lane >> 4;

  // Balanced XCD mapping.
  const int orig = blockIdx.x;                 // 1536 = 8 xcd * 192 slots
  const int xcd = orig & 7;
  const int slot = orig >> 3;                  // 0..191
  const bool isQ = slot < 64;
  int b, bn;
  if (isQ) { b = slot >> 3; bn = (slot & 7) * 128; }
  else { int s2 = slot - 64; b = s2 >> 4; bn = (s2 & 15) * 128; }
  const int i = (xcd - b) & 7;                 // m-tile index within batch
  const int bm = b * 1024 + i * 128;

  // Length-aware early exit: this m-tile's outputs are never consumed.
  const int need = isQ ? read_len(l_fr_p, b) : read_len(l_en_p, b);
  if (i * 128 >= need) return;

  const uint16_t* Bw = isQ ? wq : wkv;
  const float* bias = isQ ? bq : bkv;
  const float scale = isQ ? 0.03125f : 1.0f;
  const uint16_t* Ab = isQ ? frB : enB;
  const float* Af = isQ ? frF : enF;

  f32x4 acc[4][4];
#pragma unroll
  for (int ii = 0; ii < 4; ++ii)
#pragma unroll
    for (int j = 0; j < 4; ++j) acc[ii][j] = (f32x4){0.f, 0.f, 0.f, 0.f};

  float4 ar0[4], ar1[4];  // f32-path register staging

  auto stageB = [&](int buf, int kt) {
#pragma unroll
    for (int ii = 0; ii < 4; ++ii) {
      int g = t + 256 * ii;           // LDS slot granule (16B units)
      int L = g ^ ((g >> 3) & 7);     // logical granule it must hold
      int row = L >> 3, k8 = L & 7;
      GLDS16(Bw + (size_t)(bn + row) * 1024 + kt + k8 * 8, &Bs[buf][g * 8]);
    }
  };
  auto stageA_bf = [&](int buf, int kt) {
#pragma unroll
    for (int ii = 0; ii < 4; ++ii) {
      int g = t + 256 * ii;
      int L = g ^ ((g >> 3) & 7);
      int row = L >> 3, k8 = L & 7;
      GLDS16(Ab + (size_t)(bm + row) * 1024 + kt + k8 * 8, &As[buf][g * 8]);
    }
  };
  auto loadA_f32 = [&](int kt) {
#pragma unroll
    for (int ii = 0; ii < 4; ++ii) {
      int L = t + 256 * ii;
      int row = L >> 3, k8 = L & 7;
      const float* src = Af + (size_t)(bm + row) * 1024 + kt + k8 * 8;
      ar0[ii] = *reinterpret_cast<const float4*>(src);
      ar1[ii] = *reinterpret_cast<const float4*>(src + 4);
    }
  };
  auto writeA = [&](int buf) {
#pragma unroll
    for (int ii = 0; ii < 4; ++ii) {
      int L = t + 256 * ii;
      int row = L >> 3, k8 = L & 7;
      ushortx8 o;
      o[0] = f2bf(ar0[ii].x); o[1] = f2bf(ar0[ii].y);
      o[2] = f2bf(ar0[ii].z); o[3] = f2bf(ar0[ii].w);
      o[4] = f2bf(ar1[ii].x); o[5] = f2bf(ar1[ii].y);
      o[6] = f2bf(ar1[ii].z); o[7] = f2bf(ar1[ii].w);
      int byte = (row * 128 + k8 * 16) ^ ((row & 7) << 4);
      *reinterpret_cast<ushortx8*>(reinterpret_cast<char*>(As[buf]) + byte) = o;
    }
  };
  auto compute = [&](int buf) {
#pragma unroll
    for (int ks = 0; ks < 2; ++ks) {
      const int kb = ks * 64 + lg * 16;  // byte offset within a 128B row
      bf16x8 af[4], bf[4];
#pragma unroll
      for (int mf = 0; mf < 4; ++mf) {
        int row = wm * 64 + mf * 16 + l15;
        int byte = (row * 128 + kb) ^ ((row & 7) << 4);
        af[mf] = *reinterpret_cast<const bf16x8*>(
            reinterpret_cast<const char*>(As[buf]) + byte);
      }
#pragma unroll
      for (int nf = 0; nf < 4; ++nf) {
        int row = wn * 64 + nf * 16 + l15;
        int byte = (row * 128 + kb) ^ ((row & 7) << 4);
        bf[nf] = *reinterpret_cast<const bf16x8*>(
            reinterpret_cast<const char*>(Bs[buf]) + byte);
      }
#pragma unroll
      for (int mf = 0; mf < 4; ++mf)
#pragma unroll
        for (int nf = 0; nf < 4; ++nf)
          acc[mf][nf] = __builtin_amdgcn_mfma_f32_16x16x32_bf16(
              af[mf], bf[nf], acc[mf][nf], 0, 0, 0);
    }
  };

  // ---- prologue: fill buffer 0 with tile 0 ----
  if (ABF16) {
    stageB(0, 0);
    stageA_bf(0, 0);
  } else {
    loadA_f32(0);
    stageB(0, 0);
    writeA(0);
  }
  __syncthreads();  // drains vmcnt+lgkm: tile 0 resident

  // ---- 2-phase main loop: one barrier per K-step ----
#pragma unroll 2
  for (int tt = 0; tt < 16; ++tt) {
    const int cur = tt & 1;
    const int ktn = (tt + 1) * 64;
    if (ABF16) {
      if (tt < 15) { stageB(cur ^ 1, ktn); stageA_bf(cur ^ 1, ktn); }
      compute(cur);
    } else {
      if (tt < 15) { stageB(cur ^ 1, ktn); loadA_f32(ktn); }
      compute(cur);
      if (tt < 15) writeA(cur ^ 1);  // T14: convert+write after compute
    }
    __syncthreads();
  }

  // Epilogue: add bias, scale, scatter bf16 to attention layouts.
#pragma unroll
  for (int mf = 0; mf < 4; ++mf) {
#pragma unroll
    for (int nf = 0; nf < 4; ++nf) {
      int n = bn + wn * 64 + nf * 16 + l15;
      float bv = bias[n];
#pragma unroll
      for (int r = 0; r < 4; ++r) {
        int m = bm + wm * 64 + mf * 16 + lg * 4 + r;
        float v = (acc[mf][nf][r] + bv) * scale;
        uint16_t o = f2bf(v);
        int bb = m >> 10, s = m & 1023;
        if (isQ) {
          int h = n >> 6, d = n & 63;
          Qb[((((bb * 16 + h) << 10) | s) << 6) | d] = o;
        } else if (n < 1024) {
          int h = n >> 6, d = n & 63;
          Kb[((((bb * 16 + h) << 10) | s) << 6) | d] = o;
        } else {
          int n2 = n - 1024;
          int h = n2 >> 6, d = n2 & 63;
          Vb[((((bb * 16 + h) << 6) | d) << 10) | s] = o;
        }
      }
    }
  }
}

// ---------------- Flash attention ----------------
// 1024 blocks, QBLK=128 (each wave: 2 sub-tiles of 16 q-rows sharing staged
// K/V -> staging traffic halved). Balanced XCD mapping: XCD = h&7, so every
// XCD gets 2 heads of every batch (identical work) -> perfectly balanced.
__global__ __launch_bounds__(256) void attn_kernel(
    const uint16_t* __restrict__ Qb,  // [B,H,S,DH] bf16, pre-scaled
    const uint16_t* __restrict__ Kb,  // [B,H,S,DH] bf16
    const uint16_t* __restrict__ Vt,  // [B,H,DH,S] bf16
    const int* __restrict__ l_en_p, const int* __restrict__ l_fr_p,
    float* __restrict__ out) {        // [B,S,D] f32
  __shared__ __attribute__((aligned(16))) uint16_t Ks[64 * 64];
  __shared__ __attribute__((aligned(16))) uint16_t Vs[64 * 64];
  __shared__ __attribute__((aligned(16))) bf16_t Ps[4][16][72];
  const int t = threadIdx.x;
  const int lane = t & 63, w = t >> 6;
  const int l15 = lane & 15, lg = lane >> 4;
  // Balanced mapping: 1024 = 8 xcd * 128 slots; slot: b(3) | head-half(1) | q0(3)
  const int orig = blockIdx.x;
  const int xcd = orig & 7;
  const int slot = orig >> 3;                  // 0..127
  const int b = slot >> 4;
  const int rest = slot & 15;
  const int h = xcd + 8 * (rest >> 3);
  const int q0 = (rest & 7) << 7;              // 128-row tile
  const int bh = b * 16 + h;
  const int len_en = read_len(l_en_p, b);
  const int len_fr = read_len(l_fr_p, b);

  if (q0 >= len_fr) {
    for (int i = t; i < 128 * 64; i += 256) {
      int rr = i >> 6, cc = i & 63;
      out[(size_t)(b * 1024 + q0 + rr) * 1024 + h * 64 + cc] = 0.f;
    }
    return;
  }

  // Hoist this wave's Q fragments (2 subs x 16 rows x 64) into registers.
  bf16x8 aq[2][2];
#pragma unroll
  for (int s = 0; s < 2; ++s) {
    const uint16_t* qbase =
        Qb + ((size_t)bh * 1024 + q0 + s * 64 + w * 16 + l15) * 64 + lg * 8;
    aq[s][0] = *reinterpret_cast<const bf16x8*>(qbase);
    aq[s][1] = *reinterpret_cast<const bf16x8*>(qbase + 32);
  }

  float mrow[2][4], lrow[2][4];
  f32x4 oacc[2][4];
#pragma unroll
  for (int s = 0; s < 2; ++s)
#pragma unroll
    for (int r = 0; r < 4; ++r) {
      mrow[s][r] = -1e30f; lrow[s][r] = 0.f;
      oacc[s][r] = (f32x4){0.f, 0.f, 0.f, 0.f};
    }

  const int ntiles = (len_en + 63) >> 6;
  for (int tt = 0; tt < ntiles; ++tt) {
    const int j0 = tt * 64;
    // Stage K tile [64 j][64 d] and V tile [64 d][64 j] via GLDS,
    // linear LDS dest + swizzled global source.
#pragma unroll
    for (int i = 0; i < 2; ++i) {
      int g = t + 256 * i;
      int L = g ^ ((g >> 3) & 7);
      int row = L >> 3, k8 = L & 7;
      GLDS16(Kb + ((size_t)bh * 1024 + j0 + row) * 64 + k8 * 8, Ks + g * 8);
      GLDS16(Vt + ((size_t)bh * 64 + row) * 1024 + j0 + k8 * 8, Vs + g * 8);
    }
    __syncthreads();

#pragma unroll
    for (int s = 0; s < 2; ++s) {
      // Scores: S = Q * K^T  (16x64 per wave per sub), f32.
      f32x4 sc[4];
#pragma unroll
      for (int nf = 0; nf < 4; ++nf) sc[nf] = (f32x4){0.f, 0.f, 0.f, 0.f};
#pragma unroll
      for (int ks = 0; ks < 2; ++ks) {
        const bf16x8 a = aq[s][ks];
        const int kb = ks * 64 + lg * 16;
#pragma unroll
        for (int nf = 0; nf < 4; ++nf) {
          int row = nf * 16 + l15;
          int byte = (row * 128 + kb) ^ ((row & 7) << 4);
          bf16x8 bk = *reinterpret_cast<const bf16x8*>(
              reinterpret_cast<const char*>(Ks) + byte);
          sc[nf] = __builtin_amdgcn_mfma_f32_16x16x32_bf16(a, bk, sc[nf], 0, 0, 0);
        }
      }
      // Key mask.
#pragma unroll
      for (int nf = 0; nf < 4; ++nf) {
        int col = j0 + nf * 16 + l15;
        if (col >= len_en) sc[nf] = (f32x4){-1e30f, -1e30f, -1e30f, -1e30f};
      }
      // Row max.
      float tm[4];
#pragma unroll
      for (int r = 0; r < 4; ++r)
        tm[r] = fmaxf(fmaxf(sc[0][r], sc[1][r]), fmaxf(sc[2][r], sc[3][r]));
#pragma unroll
      for (int off = 1; off < 16; off <<= 1)
#pragma unroll
        for (int r = 0; r < 4; ++r) tm[r] = fmaxf(tm[r], __shfl_xor(tm[r], off));

      float fac[4];
#pragma unroll
      for (int r = 0; r < 4; ++r) {
        float mn = fmaxf(mrow[s][r], tm[r]);
        fac[r] = __expf(mrow[s][r] - mn);
        mrow[s][r] = mn;
      }
      // P = exp(S - m), row sums, write P to LDS (wave-private) for transpose.
      float ps[4] = {0.f, 0.f, 0.f, 0.f};
#pragma unroll
      for (int nf = 0; nf < 4; ++nf)
#pragma unroll
        for (int r = 0; r < 4; ++r) {
          float p = __expf(sc[nf][r] - mrow[s][r]);
          ps[r] += p;
          Ps[w][lg * 4 + r][nf * 16 + l15] = (bf16_t)p;
        }
#pragma unroll
      for (int off = 1; off < 16; off <<= 1)
#pragma unroll
        for (int r = 0; r < 4; ++r) ps[r] += __shfl_xor(ps[r], off);
#pragma unroll
      for (int r = 0; r < 4; ++r) lrow[s][r] = lrow[s][r] * fac[r] + ps[r];
#pragma unroll
      for (int df = 0; df < 4; ++df)
#pragma unroll
        for (int r = 0; r < 4; ++r) oacc[s][df][r] *= fac[r];

      // PV: O += P * V. (Ps wave-private; compiler inserts lgkmcnt for RAW.)
#pragma unroll
      for (int ks = 0; ks < 2; ++ks) {
        const bf16x8 pa = *reinterpret_cast<const bf16x8*>(
            &Ps[w][l15][0] + ks * 32 + lg * 8);
#pragma unroll
        for (int df = 0; df < 4; ++df) {
          int row = df * 16 + l15;
          int byte = (row * 128 + ks * 64 + lg * 16) ^ ((row & 7) << 4);
          bf16x8 bv = *reinterpret_cast<const bf16x8*>(
              reinterpret_cast<const char*>(Vs) + byte);
          oacc[s][df] =
              __builtin_amdgcn_mfma_f32_16x16x32_bf16(pa, bv, oacc[s][df], 0, 0, 0);
        }
      }
    }
    __syncthreads();
  }

  // Epilogue: normalize, store f32 (dead q-rows -> 0, matches nan_to_num).
#pragma unroll
  for (int s = 0; s < 2; ++s)
#pragma unroll
    for (int df = 0; df < 4; ++df)
#pragma unroll
      for (int r = 0; r < 4; ++r) {
        int q = q0 + s * 64 + w * 16 + lg * 4 + r;
        float inv = (q < len_fr && lrow[s][r] > 0.f) ? 1.0f / lrow[s][r] : 0.f;
        out[(size_t)(b * 1024 + q) * 1024 + h * 64 + df * 16 + l15] =
            oacc[s][df][r] * inv;
      }
}

// ---------------- launch ----------------
extern "C" void kernel_launch(void* const* d_in, const int* in_sizes, int n_in,
                              void* d_out, int out_size, void* d_ws,
                              size_t ws_size, hipStream_t stream) {
  const float* en = (const float*)d_in[0];
  const float* fr = (const float*)d_in[1];
  const int* l_en = (const int*)d_in[2];
  const int* l_fr = (const int*)d_in[3];
  const float* wq = (const float*)d_in[4];
  const float* bq = (const float*)d_in[5];
  const float* wkv = (const float*)d_in[6];
  const float* bkv = (const float*)d_in[7];
  float* out = (float*)d_out;  // output dtype is FLOAT32

  // Workspace layout (bytes):
  // wq_bf 0..2M | wkv_bf 2M..6M | Qbuf 6M..23M | Kbuf 23M..40M | Vtbuf 40M..56.6M
  // [optional] fr_bf 56.6M..73.4M | en_bf 73.4M..90.2M
  char* ws = (char*)d_ws;
  uint16_t* wq_bf = (uint16_t*)(ws);
  uint16_t* wkv_bf = (uint16_t*)(ws + 2097152);
  uint16_t* Qbuf = (uint16_t*)(ws + 6291456);
  uint16_t* Kbuf = (uint16_t*)(ws + 23068672);
  uint16_t* Vtbuf = (uint16_t*)(ws + 39845888);
  uint16_t* fr_bf = (uint16_t*)(ws + 56623104);
  uint16_t* en_bf = (uint16_t*)(ws + 73400320);
  const bool pre = ws_size >= 90177536ull;

  if (pre) {
    cvt4_kernel<<<19456, 256, 0, stream>>>(wq, wq_bf, 1048576,
                                           wkv, wkv_bf, 2097152,
                                           fr, fr_bf, 8388608,
                                           en, en_bf, 8388608,
                                           l_fr, l_en);
    gemm_fused<true><<<1536, 256, 0, stream>>>(nullptr, nullptr, fr_bf, en_bf,
                                               wq_bf, wkv_bf, bq, bkv,
                                               l_en, l_fr, Qbuf, Kbuf, Vtbuf);
  } else {
    cvt4_kernel<<<3072, 256, 0, stream>>>(wq, wq_bf, 1048576,
                                          wkv, wkv_bf, 2097152,
                                          nullptr, nullptr, 0,
                                          nullptr, nullptr, 0,
                                          nullptr, nullptr);
    gemm_fused<false><<<1536, 256, 0, stream>>>(fr, en, nullptr, nullptr,
                                                wq_bf, wkv_bf, bq, bkv,
                                                l_en, l_fr, Qbuf, Kbuf, Vtbuf);
  }

  attn_kernel<<<1024, 256, 0, stream>>>(Qbuf, Kbuf, Vtbuf, l_en, l_fr, out);
}

// Round 12
// 115.561 us; speedup vs baseline: 1.9258x; 1.1681x over previous
//
#include <hip/hip_runtime.h>
#include <hip/hip_bf16.h>
#include <stdint.h>

// Problem constants: B=8, S=1024, D=1024, H=16, DH=64
typedef __bf16 bf16_t;
typedef bf16_t bf16x8 __attribute__((ext_vector_type(8)));
typedef float f32x4 __attribute__((ext_vector_type(4)));
typedef unsigned short ushortx8 __attribute__((ext_vector_type(8)));

__device__ __forceinline__ uint16_t f2bf(float f) {
  uint32_t u = __float_as_uint(f);
  uint32_t r = u + 0x7FFFu + ((u >> 16) & 1u);  // RNE
  return (uint16_t)(r >> 16);
}

__device__ __forceinline__ int read_len(const int* __restrict__ p, int b) {
  bool is64 = (p[1] == 0) | (p[3] == 0) | (p[5] == 0) | (p[7] == 0);
  return is64 ? p[2 * b] : p[b];
}

#define GLDS16(gp, lp)                                                   \
  __builtin_amdgcn_global_load_lds(                                      \
      (const __attribute__((address_space(1))) uint32_t*)(gp),           \
      (__attribute__((address_space(3))) uint32_t*)(lp), 16, 0, 0)

// ------ merged f32 -> bf16 convert over up to 4 segments (granule = 4) ------
__global__ void cvt4_kernel(const float* __restrict__ s0, uint16_t* __restrict__ d0, int n0,
                            const float* __restrict__ s1, uint16_t* __restrict__ d1, int n1,
                            const float* __restrict__ s2, uint16_t* __restrict__ d2, int n2,
                            const float* __restrict__ s3, uint16_t* __restrict__ d3, int n3,
                            const int* __restrict__ msk2, const int* __restrict__ msk3) {
  int e = (blockIdx.x * blockDim.x + threadIdx.x) * 4;
  const float* s;
  uint16_t* d;
  const int* msk = nullptr;
  if (e < n0) { s = s0 + e; d = d0 + e; }
  else if ((e -= n0) < n1) { s = s1 + e; d = d1 + e; }
  else if ((e -= n1) < n2) { s = s2 + e; d = d2 + e; msk = msk2; }
  else if ((e -= n2) < n3) { s = s3 + e; d = d3 + e; msk = msk3; }
  else return;
  if (msk) {
    int row = (e >> 10) & 1023, b = e >> 20;   // 1024 elems/row, 1M elems/batch
    int need = (read_len(msk, b) + 127) & ~127;
    if (row >= need) return;
  }
  const float4 v = *reinterpret_cast<const float4*>(s);
  ushort4 o;
  o.x = f2bf(v.x); o.y = f2bf(v.y); o.z = f2bf(v.z); o.w = f2bf(v.w);
  *reinterpret_cast<ushort4*>(d) = o;
}

// -------- Fused NT GEMM: Q = fr@wq^T+bq (scaled), KV = en@wkv^T+bkv --------
// (unchanged from r11: balanced XCD mapping, 2-phase dbuf, length early-exit)
template <bool ABF16>
__global__ __launch_bounds__(256) void gemm_fused(
    const float* __restrict__ frF, const float* __restrict__ enF,
    const uint16_t* __restrict__ frB, const uint16_t* __restrict__ enB,
    const uint16_t* __restrict__ wq, const uint16_t* __restrict__ wkv,
    const float* __restrict__ bq, const float* __restrict__ bkv,
    const int* __restrict__ l_en_p, const int* __restrict__ l_fr_p,
    uint16_t* __restrict__ Qb,       // [B,H,S,DH] bf16, pre-scaled
    uint16_t* __restrict__ Kb,       // [B,H,S,DH] bf16
    uint16_t* __restrict__ Vb) {     // [B,H,DH,S] bf16
  __shared__ __attribute__((aligned(16))) uint16_t As[2][128 * 64];
  __shared__ __attribute__((aligned(16))) uint16_t Bs[2][128 * 64];
  const int t = threadIdx.x;
  const int lane = t & 63;
  const int w = t >> 6;
  const int wm = w >> 1, wn = w & 1;
  const int l15 = lane & 15, lg = lane >> 4;

  const int orig = blockIdx.x;                 // 1536 = 8 xcd * 192 slots
  const int xcd = orig & 7;
  const int slot = orig >> 3;                  // 0..191
  const bool isQ = slot < 64;
  int b, bn;
  if (isQ) { b = slot >> 3; bn = (slot & 7) * 128; }
  else { int s2 = slot - 64; b = s2 >> 4; bn = (s2 & 15) * 128; }
  const int i = (xcd - b) & 7;                 // m-tile index within batch
  const int bm = b * 1024 + i * 128;

  const int need = isQ ? read_len(l_fr_p, b) : read_len(l_en_p, b);
  if (i * 128 >= need) return;

  const uint16_t* Bw = isQ ? wq : wkv;
  const float* bias = isQ ? bq : bkv;
  const float scale = isQ ? 0.03125f : 1.0f;
  const uint16_t* Ab = isQ ? frB : enB;
  const float* Af = isQ ? frF : enF;

  f32x4 acc[4][4];
#pragma unroll
  for (int ii = 0; ii < 4; ++ii)
#pragma unroll
    for (int j = 0; j < 4; ++j) acc[ii][j] = (f32x4){0.f, 0.f, 0.f, 0.f};

  float4 ar0[4], ar1[4];  // f32-path register staging

  auto stageB = [&](int buf, int kt) {
#pragma unroll
    for (int ii = 0; ii < 4; ++ii) {
      int g = t + 256 * ii;           // LDS slot granule (16B units)
      int L = g ^ ((g >> 3) & 7);     // logical granule it must hold
      int row = L >> 3, k8 = L & 7;
      GLDS16(Bw + (size_t)(bn + row) * 1024 + kt + k8 * 8, &Bs[buf][g * 8]);
    }
  };
  auto stageA_bf = [&](int buf, int kt) {
#pragma unroll
    for (int ii = 0; ii < 4; ++ii) {
      int g = t + 256 * ii;
      int L = g ^ ((g >> 3) & 7);
      int row = L >> 3, k8 = L & 7;
      GLDS16(Ab + (size_t)(bm + row) * 1024 + kt + k8 * 8, &As[buf][g * 8]);
    }
  };
  auto loadA_f32 = [&](int kt) {
#pragma unroll
    for (int ii = 0; ii < 4; ++ii) {
      int L = t + 256 * ii;
      int row = L >> 3, k8 = L & 7;
      const float* src = Af + (size_t)(bm + row) * 1024 + kt + k8 * 8;
      ar0[ii] = *reinterpret_cast<const float4*>(src);
      ar1[ii] = *reinterpret_cast<const float4*>(src + 4);
    }
  };
  auto writeA = [&](int buf) {
#pragma unroll
    for (int ii = 0; ii < 4; ++ii) {
      int L = t + 256 * ii;
      int row = L >> 3, k8 = L & 7;
      ushortx8 o;
      o[0] = f2bf(ar0[ii].x); o[1] = f2bf(ar0[ii].y);
      o[2] = f2bf(ar0[ii].z); o[3] = f2bf(ar0[ii].w);
      o[4] = f2bf(ar1[ii].x); o[5] = f2bf(ar1[ii].y);
      o[6] = f2bf(ar1[ii].z); o[7] = f2bf(ar1[ii].w);
      int byte = (row * 128 + k8 * 16) ^ ((row & 7) << 4);
      *reinterpret_cast<ushortx8*>(reinterpret_cast<char*>(As[buf]) + byte) = o;
    }
  };
  auto compute = [&](int buf) {
#pragma unroll
    for (int ks = 0; ks < 2; ++ks) {
      const int kb = ks * 64 + lg * 16;  // byte offset within a 128B row
      bf16x8 af[4], bf[4];
#pragma unroll
      for (int mf = 0; mf < 4; ++mf) {
        int row = wm * 64 + mf * 16 + l15;
        int byte = (row * 128 + kb) ^ ((row & 7) << 4);
        af[mf] = *reinterpret_cast<const bf16x8*>(
            reinterpret_cast<const char*>(As[buf]) + byte);
      }
#pragma unroll
      for (int nf = 0; nf < 4; ++nf) {
        int row = wn * 64 + nf * 16 + l15;
        int byte = (row * 128 + kb) ^ ((row & 7) << 4);
        bf[nf] = *reinterpret_cast<const bf16x8*>(
            reinterpret_cast<const char*>(Bs[buf]) + byte);
      }
#pragma unroll
      for (int mf = 0; mf < 4; ++mf)
#pragma unroll
        for (int nf = 0; nf < 4; ++nf)
          acc[mf][nf] = __builtin_amdgcn_mfma_f32_16x16x32_bf16(
              af[mf], bf[nf], acc[mf][nf], 0, 0, 0);
    }
  };

  if (ABF16) {
    stageB(0, 0);
    stageA_bf(0, 0);
  } else {
    loadA_f32(0);
    stageB(0, 0);
    writeA(0);
  }
  __syncthreads();

#pragma unroll 2
  for (int tt = 0; tt < 16; ++tt) {
    const int cur = tt & 1;
    const int ktn = (tt + 1) * 64;
    if (ABF16) {
      if (tt < 15) { stageB(cur ^ 1, ktn); stageA_bf(cur ^ 1, ktn); }
      compute(cur);
    } else {
      if (tt < 15) { stageB(cur ^ 1, ktn); loadA_f32(ktn); }
      compute(cur);
      if (tt < 15) writeA(cur ^ 1);
    }
    __syncthreads();
  }

#pragma unroll
  for (int mf = 0; mf < 4; ++mf) {
#pragma unroll
    for (int nf = 0; nf < 4; ++nf) {
      int n = bn + wn * 64 + nf * 16 + l15;
      float bv = bias[n];
#pragma unroll
      for (int r = 0; r < 4; ++r) {
        int m = bm + wm * 64 + mf * 16 + lg * 4 + r;
        float v = (acc[mf][nf][r] + bv) * scale;
        uint16_t o = f2bf(v);
        int bb = m >> 10, s = m & 1023;
        if (isQ) {
          int h = n >> 6, d = n & 63;
          Qb[((((bb * 16 + h) << 10) | s) << 6) | d] = o;
        } else if (n < 1024) {
          int h = n >> 6, d = n & 63;
          Kb[((((bb * 16 + h) << 10) | s) << 6) | d] = o;
        } else {
          int n2 = n - 1024;
          int h = n2 >> 6, d = n2 & 63;
          Vb[((((bb * 16 + h) << 6) | d) << 10) | s] = o;
        }
      }
    }
  }
}

// ---------------- Flash attention ----------------
// 1024 blocks x 512 threads (8 waves). QBLK=128: wave w owns rows
// [q0+16w, q0+16w+16). K/V double-buffered (2-phase), defer-max (THR=8).
// Balanced XCD mapping: XCD = h&7 (every XCD gets 2 heads of every batch).
__global__ __launch_bounds__(512) void attn_kernel(
    const uint16_t* __restrict__ Qb,  // [B,H,S,DH] bf16, pre-scaled
    const uint16_t* __restrict__ Kb,  // [B,H,S,DH] bf16
    const uint16_t* __restrict__ Vt,  // [B,H,DH,S] bf16
    const int* __restrict__ l_en_p, const int* __restrict__ l_fr_p,
    float* __restrict__ out) {        // [B,S,D] f32
  __shared__ __attribute__((aligned(16))) uint16_t Ks[2][64 * 64];
  __shared__ __attribute__((aligned(16))) uint16_t Vs[2][64 * 64];
  __shared__ __attribute__((aligned(16))) bf16_t Ps[8][16][72];
  const int t = threadIdx.x;
  const int lane = t & 63, w = t >> 6;          // w in 0..7
  const int l15 = lane & 15, lg = lane >> 4;
  // Balanced mapping: 1024 = 8 xcd * 128 slots; slot: b(3) | head-half(1) | q0(3)
  const int orig = blockIdx.x;
  const int xcd = orig & 7;
  const int slot = orig >> 3;                  // 0..127
  const int b = slot >> 4;
  const int rest = slot & 15;
  const int h = xcd + 8 * (rest >> 3);
  const int q0 = (rest & 7) << 7;              // 128-row tile
  const int bh = b * 16 + h;
  const int len_en = read_len(l_en_p, b);
  const int len_fr = read_len(l_fr_p, b);

  if (q0 >= len_fr) {
    for (int i = t; i < 128 * 64; i += 512) {
      int rr = i >> 6, cc = i & 63;
      out[(size_t)(b * 1024 + q0 + rr) * 1024 + h * 64 + cc] = 0.f;
    }
    return;
  }

  // Hoist this wave's Q fragments (16 rows x 64) into registers.
  const uint16_t* qbase =
      Qb + ((size_t)bh * 1024 + q0 + w * 16 + l15) * 64 + lg * 8;
  const bf16x8 aq0 = *reinterpret_cast<const bf16x8*>(qbase);
  const bf16x8 aq1 = *reinterpret_cast<const bf16x8*>(qbase + 32);

  float mrow[4], lrow[4];
  f32x4 oacc[4];
#pragma unroll
  for (int r = 0; r < 4; ++r) { mrow[r] = -1e30f; lrow[r] = 0.f; }
#pragma unroll
  for (int df = 0; df < 4; ++df) oacc[df] = (f32x4){0.f, 0.f, 0.f, 0.f};

  // Stage K tile [64 j][64 d] and V tile [64 d][64 j] into buf via GLDS:
  // 512 threads -> 1 granule (16B) each per matrix. Linear LDS dest +
  // pre-swizzled global source (read side XORs (row&7)<<4).
  auto stage = [&](int buf, int j0) {
    int g = t;
    int L = g ^ ((g >> 3) & 7);
    int row = L >> 3, k8 = L & 7;
    GLDS16(Kb + ((size_t)bh * 1024 + j0 + row) * 64 + k8 * 8, &Ks[buf][g * 8]);
    GLDS16(Vt + ((size_t)bh * 64 + row) * 1024 + j0 + k8 * 8, &Vs[buf][g * 8]);
  };

  const int ntiles = (len_en + 63) >> 6;
  stage(0, 0);
  __syncthreads();

  for (int tt = 0; tt < ntiles; ++tt) {
    const int cur = tt & 1;
    const int j0 = tt * 64;
    if (tt + 1 < ntiles) stage(cur ^ 1, (tt + 1) * 64);

    // Scores: S = Q * K^T  (16x64 per wave), f32.
    f32x4 sc[4];
#pragma unroll
    for (int nf = 0; nf < 4; ++nf) sc[nf] = (f32x4){0.f, 0.f, 0.f, 0.f};
#pragma unroll
    for (int ks = 0; ks < 2; ++ks) {
      const bf16x8 aq = ks ? aq1 : aq0;
      const int kb = ks * 64 + lg * 16;
#pragma unroll
      for (int nf = 0; nf < 4; ++nf) {
        int row = nf * 16 + l15;
        int byte = (row * 128 + kb) ^ ((row & 7) << 4);
        bf16x8 bk = *reinterpret_cast<const bf16x8*>(
            reinterpret_cast<const char*>(Ks[cur]) + byte);
        sc[nf] = __builtin_amdgcn_mfma_f32_16x16x32_bf16(aq, bk, sc[nf], 0, 0, 0);
      }
    }
    // Key mask.
#pragma unroll
    for (int nf = 0; nf < 4; ++nf) {
      int col = j0 + nf * 16 + l15;
      if (col >= len_en) sc[nf] = (f32x4){-1e30f, -1e30f, -1e30f, -1e30f};
    }
    // Row max (4 nf, then 16-lane row group).
    float tm[4];
#pragma unroll
    for (int r = 0; r < 4; ++r)
      tm[r] = fmaxf(fmaxf(sc[0][r], sc[1][r]), fmaxf(sc[2][r], sc[3][r]));
#pragma unroll
    for (int off = 1; off < 16; off <<= 1)
#pragma unroll
      for (int r = 0; r < 4; ++r) tm[r] = fmaxf(tm[r], __shfl_xor(tm[r], off));

    // Defer-max (T13): only rescale when some row's max grew by > 8.
    bool small = (tm[0] <= mrow[0] + 8.f) && (tm[1] <= mrow[1] + 8.f) &&
                 (tm[2] <= mrow[2] + 8.f) && (tm[3] <= mrow[3] + 8.f);
    if (!__all(small)) {
      float fac[4];
#pragma unroll
      for (int r = 0; r < 4; ++r) {
        float mn = fmaxf(mrow[r], tm[r]);
        fac[r] = __expf(mrow[r] - mn);
        mrow[r] = mn;
      }
#pragma unroll
      for (int r = 0; r < 4; ++r) lrow[r] *= fac[r];
#pragma unroll
      for (int df = 0; df < 4; ++df)
#pragma unroll
        for (int r = 0; r < 4; ++r) oacc[df][r] *= fac[r];
    }
    // P = exp(S - m) (bounded by e^8), row sums, P -> LDS for transpose.
    float ps[4] = {0.f, 0.f, 0.f, 0.f};
#pragma unroll
    for (int nf = 0; nf < 4; ++nf)
#pragma unroll
      for (int r = 0; r < 4; ++r) {
        float p = __expf(sc[nf][r] - mrow[r]);
        ps[r] += p;
        Ps[w][lg * 4 + r][nf * 16 + l15] = (bf16_t)p;
      }
#pragma unroll
    for (int off = 1; off < 16; off <<= 1)
#pragma unroll
      for (int r = 0; r < 4; ++r) ps[r] += __shfl_xor(ps[r], off);
#pragma unroll
    for (int r = 0; r < 4; ++r) lrow[r] += ps[r];

    // PV: O += P * V. (Ps wave-private; compiler inserts lgkmcnt for RAW.)
#pragma unroll
    for (int ks = 0; ks < 2; ++ks) {
      const bf16x8 pa = *reinterpret_cast<const bf16x8*>(
          &Ps[w][l15][0] + ks * 32 + lg * 8);
#pragma unroll
      for (int df = 0; df < 4; ++df) {
        int row = df * 16 + l15;
        int byte = (row * 128 + ks * 64 + lg * 16) ^ ((row & 7) << 4);
        bf16x8 bv = *reinterpret_cast<const bf16x8*>(
            reinterpret_cast<const char*>(Vs[cur]) + byte);
        oacc[df] = __builtin_amdgcn_mfma_f32_16x16x32_bf16(pa, bv, oacc[df], 0, 0, 0);
      }
    }
    __syncthreads();
  }

  // Epilogue: normalize, store f32 (dead q-rows -> 0, matches nan_to_num).
#pragma unroll
  for (int df = 0; df < 4; ++df)
#pragma unroll
    for (int r = 0; r < 4; ++r) {
      int q = q0 + w * 16 + lg * 4 + r;
      float inv = (q < len_fr && lrow[r] > 0.f) ? 1.0f / lrow[r] : 0.f;
      out[(size_t)(b * 1024 + q) * 1024 + h * 64 + df * 16 + l15] =
          oacc[df][r] * inv;
    }
}

// ---------------- launch ----------------
extern "C" void kernel_launch(void* const* d_in, const int* in_sizes, int n_in,
                              void* d_out, int out_size, void* d_ws,
                              size_t ws_size, hipStream_t stream) {
  const float* en = (const float*)d_in[0];
  const float* fr = (const float*)d_in[1];
  const int* l_en = (const int*)d_in[2];
  const int* l_fr = (const int*)d_in[3];
  const float* wq = (const float*)d_in[4];
  const float* bq = (const float*)d_in[5];
  const float* wkv = (const float*)d_in[6];
  const float* bkv = (const float*)d_in[7];
  float* out = (float*)d_out;  // output dtype is FLOAT32

  // Workspace layout (bytes):
  // wq_bf 0..2M | wkv_bf 2M..6M | Qbuf 6M..23M | Kbuf 23M..40M | Vtbuf 40M..56.6M
  // [optional] fr_bf 56.6M..73.4M | en_bf 73.4M..90.2M
  char* ws = (char*)d_ws;
  uint16_t* wq_bf = (uint16_t*)(ws);
  uint16_t* wkv_bf = (uint16_t*)(ws + 2097152);
  uint16_t* Qbuf = (uint16_t*)(ws + 6291456);
  uint16_t* Kbuf = (uint16_t*)(ws + 23068672);
  uint16_t* Vtbuf = (uint16_t*)(ws + 39845888);
  uint16_t* fr_bf = (uint16_t*)(ws + 56623104);
  uint16_t* en_bf = (uint16_t*)(ws + 73400320);
  const bool pre = ws_size >= 90177536ull;

  if (pre) {
    cvt4_kernel<<<19456, 256, 0, stream>>>(wq, wq_bf, 1048576,
                                           wkv, wkv_bf, 2097152,
                                           fr, fr_bf, 8388608,
                                           en, en_bf, 8388608,
                                           l_fr, l_en);
    gemm_fused<true><<<1536, 256, 0, stream>>>(nullptr, nullptr, fr_bf, en_bf,
                                               wq_bf, wkv_bf, bq, bkv,
                                               l_en, l_fr, Qbuf, Kbuf, Vtbuf);
  } else {
    cvt4_kernel<<<3072, 256, 0, stream>>>(wq, wq_bf, 1048576,
                                          wkv, wkv_bf, 2097152,
                                          nullptr, nullptr, 0,
                                          nullptr, nullptr, 0,
                                          nullptr, nullptr);
    gemm_fused<false><<<1536, 256, 0, stream>>>(fr, en, nullptr, nullptr,
                                                wq_bf, wkv_bf, bq, bkv,
                                                l_en, l_fr, Qbuf, Kbuf, Vtbuf);
  }

  attn_kernel<<<1024, 512, 0, stream>>>(Qbuf, Kbuf, Vtbuf, l_en, l_fr, out);
}